// Round 1
// baseline (1370.424 us; speedup 1.0000x reference)
//
#include <hip/hip_runtime.h>
#include <cstdint>

// ---------------------------------------------------------------------------
// TenGCN fused forward. 128 graphs (2 branches x 64 batches), one WG/graph
// for the graph stages. h1/h2 are algebraically eliminated via
// W01 = Wm0b @ W_gcn1; the tcl/concat/fuse/mean chain collapses to small
// precomputed weight vectors (k0_setup).
// ---------------------------------------------------------------------------

constexpr int B_ = 64, N_ = 1024, E_ = 32768, F_ = 128, H_ = 32;
constexpr int CF_ = 5, P_ = 50, K_ = 512, G_ = 128, PO = 25;

// workspace offsets (in floats)
constexpr size_t WS_HS    = 0;                               // G*N*10  (x @ W_score)
constexpr size_t WS_NIDX  = WS_HS + (size_t)G_*N_*10;        // G*N ints (new index or -1)
constexpr size_t WS_PAIRS = WS_NIDX + (size_t)G_*N_;         // G*E uint32 packed (ss|dd<<16)
constexpr size_t WS_MR0   = WS_PAIRS + (size_t)G_*E_;        // G*32 mean(relu(a0))
constexpr size_t WS_MR1   = WS_MR0 + (size_t)G_*H_;          // G*32 mean(relu(a1))
constexpr size_t WS_PPI   = WS_MR1 + (size_t)G_*H_;          // G*25
constexpr size_t WS_H0M   = WS_PPI + (size_t)G_*PO;          // 64
constexpr size_t WS_H2M   = WS_H0M + 64;                     // 32
constexpr size_t WS_F0V   = WS_H2M + 32;                     // 2
constexpr size_t WS_F2V   = WS_F0V + 2;                      // 32
constexpr size_t WS_G0V   = WS_F2V + 32;                     // 32
constexpr size_t WS_G2V   = WS_G0V + 32;                     // 25 (pad to 32)
constexpr size_t WS_B01   = WS_G2V + 32;                     // 32
constexpr size_t WS_W01   = WS_B01 + 32;                     // 1024

// ---------------------------------------------------------------------------
// k0: tiny precomputations.
//   block 0: h0m/h2m/f0v/f2v/g0v/g2v/b01 ; blocks 1..4: W01 = Wm0b @ W_gcn1
// ---------------------------------------------------------------------------
__global__ __launch_bounds__(256) void k0_setup(
    const float* __restrict__ F0w, const float* __restrict__ F2w,
    const float* __restrict__ G0w, const float* __restrict__ G2w,
    const float* __restrict__ H0w, const float* __restrict__ H2w,
    const float* __restrict__ Wm0b, const float* __restrict__ bm0b,
    const float* __restrict__ Wg1, float* __restrict__ ws)
{
  int t = threadIdx.x;
  if (blockIdx.x == 0) {
    __shared__ float h0m[64], h2m[32];
    if (t < 64) { float s = 0.f; for (int p = 0; p < 64; ++p) s += H0w[p*64+t]; h0m[t] = s*(1.f/64.f); }
    if (t < 32) { float s = 0.f; for (int r = 0; r < 32; ++r) s += H2w[r*32+t]; h2m[t] = s*(1.f/32.f); }
    __syncthreads();
    if (t < 64) ws[WS_H0M+t] = h0m[t];
    if (t < 32) ws[WS_H2M+t] = h2m[t];
    if (t < 2)  { float s=0.f; for (int p=0;p<32;++p) s += F0w[p*2+t]*h0m[p];     ws[WS_F0V+t]=s; }
    if (t < 32) { float s=0.f; for (int r=0;r<32;++r) s += F2w[r*32+t]*h2m[r];    ws[WS_F2V+t]=s; }
    if (t < 32) { float s=0.f; for (int p=0;p<32;++p) s += G0w[p*32+t]*h0m[32+p]; ws[WS_G0V+t]=s; }
    if (t < PO) { float s=0.f; for (int r=0;r<32;++r) s += G2w[r*25+t]*h2m[r];    ws[WS_G2V+t]=s; }
    if (t < 32) { float s=0.f; for (int k=0;k<1024;++k) s += bm0b[k]*Wg1[k*32+t]; ws[WS_B01+t]=s; }
  } else {
    int o = (blockIdx.x-1)*256 + t;       // 0..1023 across blocks 1..4
    int kk = o >> 5, j = o & 31;
    float s = 0.f;
    for (int tt = 0; tt < 1024; ++tt) s += Wm0b[kk*1024+tt]*Wg1[tt*32+j];
    ws[WS_W01+o] = s;
  }
}

// ---------------------------------------------------------------------------
// k1: hs[g][n][0..9] = x[g][n][:] @ W_score      grid (G,4) x 256
// ---------------------------------------------------------------------------
__global__ __launch_bounds__(256) void k1_scorefeat(
    const float* __restrict__ x1, const float* __restrict__ x2,
    const float* __restrict__ Wsc, float* __restrict__ ws)
{
  int g = blockIdx.x, br = g >> 6, b = g & 63;
  const float* xg = (br ? x2 : x1) + (size_t)b*N_*F_;
  __shared__ float Ws[F_*10];
  int t = threadIdx.x;
  for (int i = t; i < F_*10; i += 256) Ws[i] = Wsc[i];
  __syncthreads();
  int n = blockIdx.y*256 + t;
  const float4* xr = (const float4*)(xg + (size_t)n*F_);
  float acc[10] = {};
  for (int k4 = 0; k4 < 32; ++k4) {
    float4 v = xr[k4];
    const float* w = &Ws[k4*40];
    #pragma unroll
    for (int j = 0; j < 10; ++j)
      acc[j] += v.x*w[j] + v.y*w[10+j] + v.z*w[20+j] + v.w*w[30+j];
  }
  float* o = ws + WS_HS + ((size_t)g*N_ + n)*10;
  #pragma unroll
  for (int j = 0; j < 10; ++j) o[j] = acc[j];
}

// ---------------------------------------------------------------------------
// k2: scoring GCN + top-512 selection (bitonic sort, desc score / asc idx).
// One WG of 1024 threads per graph. ~96KB LDS.
// ---------------------------------------------------------------------------
__global__ __launch_bounds__(1024) void k2_pool(
    const int* __restrict__ ei1, const int* __restrict__ ei2,
    const float* __restrict__ bsc, float* __restrict__ ws)
{
  int g = blockIdx.x, br = g >> 6, b = g & 63;
  const int* ei  = (br ? ei2 : ei1) + (size_t)b*2*E_;
  const int* src = ei;
  const int* dst = ei + E_;
  __shared__ float hsL[N_*10];
  __shared__ float aggL[N_*10];
  __shared__ float degL[N_];
  __shared__ float keyL[N_];
  __shared__ int   idxL[N_];
  __shared__ int   nidxL[N_];
  int t = threadIdx.x;
  const float* hsg = ws + WS_HS + (size_t)g*N_*10;
  for (int i = t; i < N_*10; i += 1024) { hsL[i] = hsg[i]; aggL[i] = 0.f; }
  degL[t] = 0.f;
  __syncthreads();
  for (int e = t; e < E_; e += 1024) atomicAdd(&degL[dst[e]], 1.0f);
  __syncthreads();
  degL[t] = rsqrtf(degL[t] + 1.0f);          // now dinv
  __syncthreads();
  for (int e = t; e < E_; e += 1024) {
    int s = src[e], d = dst[e];
    float c = degL[s]*degL[d];
    int bs = s*10, bd = d*10;
    #pragma unroll
    for (int j = 0; j < 10; ++j) atomicAdd(&aggL[bd+j], hsL[bs+j]*c);
  }
  __syncthreads();
  { float dv = degL[t], d2 = dv*dv, sc = 0.f;
    #pragma unroll
    for (int j = 0; j < 5; ++j) {
      float e0 = aggL[t*10+2*j]   + hsL[t*10+2*j]*d2   + bsc[2*j];
      float e1 = aggL[t*10+2*j+1] + hsL[t*10+2*j+1]*d2 + bsc[2*j+1];
      sc += fabsf(e1-e0);
    }
    keyL[t] = sc; idxL[t] = t; }
  __syncthreads();
  // bitonic sort: precedence = (score desc, idx asc)
  for (int k = 2; k <= N_; k <<= 1) {
    for (int j = k >> 1; j > 0; j >>= 1) {
      int ixj = t ^ j;
      if (ixj > t) {
        float ka = keyL[t], kb = keyL[ixj];
        int   ia = idxL[t], ib = idxL[ixj];
        bool aAfter = (ka < kb) || (ka == kb && ia > ib);
        bool doSwap = ((t & k) == 0) ? aAfter : !aAfter;
        if (doSwap) { keyL[t]=kb; keyL[ixj]=ka; idxL[t]=ib; idxL[ixj]=ia; }
      }
      __syncthreads();
    }
  }
  nidxL[t] = -1;
  __syncthreads();
  if (t < K_) nidxL[idxL[t]] = t;
  __syncthreads();
  ((int*)(ws + WS_NIDX))[(size_t)g*N_ + t] = nidxL[t];
}

// ---------------------------------------------------------------------------
// small 512x32 @ 32x32 LDS matmul, W padded [32][36], 4x4 reg tiles,
// k-rotation by 'it' to keep A-side ds_read_b128 conflict-free.
// ---------------------------------------------------------------------------
static __device__ __forceinline__ void mm32(
    const float* __restrict__ S, float* __restrict__ D,
    const float* __restrict__ Wp, const float* __restrict__ bias,
    bool do_relu, int it, int jt)
{
  const int i0 = it*4, j0 = jt*4;
  float acc[4][4] = {};
  #pragma unroll
  for (int kv = 0; kv < 8; ++kv) {
    int k4 = (kv + it) & 7;
    float4 w0 = *(const float4*)&Wp[(k4*4+0)*36 + j0];
    float4 w1 = *(const float4*)&Wp[(k4*4+1)*36 + j0];
    float4 w2 = *(const float4*)&Wp[(k4*4+2)*36 + j0];
    float4 w3 = *(const float4*)&Wp[(k4*4+3)*36 + j0];
    #pragma unroll
    for (int d = 0; d < 4; ++d) {
      float4 a = *(const float4*)&S[(i0+d)*32 + k4*4];
      acc[d][0] += a.x*w0.x + a.y*w1.x + a.z*w2.x + a.w*w3.x;
      acc[d][1] += a.x*w0.y + a.y*w1.y + a.z*w2.y + a.w*w3.y;
      acc[d][2] += a.x*w0.z + a.y*w1.z + a.z*w2.z + a.w*w3.z;
      acc[d][3] += a.x*w0.w + a.y*w1.w + a.z*w2.w + a.w*w3.w;
    }
  }
  float b0 = bias[j0+0], b1 = bias[j0+1], b2 = bias[j0+2], b3 = bias[j0+3];
  #pragma unroll
  for (int d = 0; d < 4; ++d) {
    float v0 = acc[d][0]+b0, v1 = acc[d][1]+b1, v2 = acc[d][2]+b2, v3 = acc[d][3]+b3;
    if (do_relu) { v0=fmaxf(v0,0.f); v1=fmaxf(v1,0.f); v2=fmaxf(v2,0.f); v3=fmaxf(v3,0.f); }
    D[(i0+d)*32 + j0+0] = v0; D[(i0+d)*32 + j0+1] = v1;
    D[(i0+d)*32 + j0+2] = v2; D[(i0+d)*32 + j0+3] = v3;
  }
}

// ---------------------------------------------------------------------------
// k3: per-graph pooled pipeline: gather+x@Wg0, conv0, relu-MLP0a, mean,
//     hnew = r0@W01+b01, conv1, relu-MLP1a, mean.  1024 thr, ~154KB LDS.
// ---------------------------------------------------------------------------
__global__ __launch_bounds__(1024) void k3_graph(
    const float* __restrict__ x1, const float* __restrict__ x2,
    const int* __restrict__ ei1, const int* __restrict__ ei2,
    const float* __restrict__ Wg0, const float* __restrict__ bg0,
    const float* __restrict__ Wm0a, const float* __restrict__ bm0a,
    const float* __restrict__ bg1, const float* __restrict__ Wm1a,
    const float* __restrict__ bm1a, float* __restrict__ ws)
{
  int g = blockIdx.x, br = g >> 6, b = g & 63;
  const float* xg = (br ? x2 : x1) + (size_t)b*N_*F_;
  const int* ei  = (br ? ei2 : ei1) + (size_t)b*2*E_;
  const int* src = ei;
  const int* dst = ei + E_;
  const int* nidxg = ((const int*)(ws + WS_NIDX)) + (size_t)g*N_;
  uint32_t* pairs = ((uint32_t*)(ws + WS_PAIRS)) + (size_t)g*E_;

  __shared__ float hb[K_*H_];     // 64KB
  __shared__ float ab[K_*H_];     // 64KB
  __shared__ float dinv[K_];      // 2KB
  __shared__ float wbuf[4608];    // 18KB  (Wg0 [128][36]; later 3x [32][36])
  __shared__ int   nidx[N_];      // 4KB
  __shared__ int   perm[K_];      // 2KB
  __shared__ int   cntL;

  const int t = threadIdx.x;
  const int it = t >> 3, jt = t & 7;
  const int i0 = it*4, j0 = jt*4;

  // phase 0: loads
  nidx[t] = nidxg[t];
  if (t < K_) dinv[t] = 0.f;
  if (t == 0) cntL = 0;
  for (int i = t; i < F_*H_; i += 1024) { int k = i >> 5, j = i & 31; wbuf[k*36 + j] = Wg0[i]; }
  __syncthreads();

  // phase 1: perm, degree, compact valid edges
  { int ii = nidx[t]; if (ii >= 0) perm[ii] = t; }
  for (int e = t; e < E_; e += 1024) {
    int ss = nidx[src[e]], dd = nidx[dst[e]];
    if ((ss | dd) >= 0) {
      atomicAdd(&dinv[dd], 1.0f);
      int pos = atomicAdd(&cntL, 1);
      pairs[pos] = (uint32_t)ss | ((uint32_t)dd << 16);
    }
  }
  __syncthreads();
  const int cnt = cntL;

  // phase 2: hb = X[perm] @ Wg0  (4x4 reg tile, A from global via L1 broadcast)
  {
    const float* xr0 = xg + (size_t)perm[i0+0]*F_;
    const float* xr1 = xg + (size_t)perm[i0+1]*F_;
    const float* xr2 = xg + (size_t)perm[i0+2]*F_;
    const float* xr3 = xg + (size_t)perm[i0+3]*F_;
    float acc[4][4] = {};
    for (int k4 = 0; k4 < 32; ++k4) {
      float4 w0 = *(const float4*)&wbuf[(k4*4+0)*36 + j0];
      float4 w1 = *(const float4*)&wbuf[(k4*4+1)*36 + j0];
      float4 w2 = *(const float4*)&wbuf[(k4*4+2)*36 + j0];
      float4 w3 = *(const float4*)&wbuf[(k4*4+3)*36 + j0];
      float4 a;
      a = *(const float4*)(xr0 + k4*4);
      acc[0][0]+=a.x*w0.x+a.y*w1.x+a.z*w2.x+a.w*w3.x; acc[0][1]+=a.x*w0.y+a.y*w1.y+a.z*w2.y+a.w*w3.y;
      acc[0][2]+=a.x*w0.z+a.y*w1.z+a.z*w2.z+a.w*w3.z; acc[0][3]+=a.x*w0.w+a.y*w1.w+a.z*w2.w+a.w*w3.w;
      a = *(const float4*)(xr1 + k4*4);
      acc[1][0]+=a.x*w0.x+a.y*w1.x+a.z*w2.x+a.w*w3.x; acc[1][1]+=a.x*w0.y+a.y*w1.y+a.z*w2.y+a.w*w3.y;
      acc[1][2]+=a.x*w0.z+a.y*w1.z+a.z*w2.z+a.w*w3.z; acc[1][3]+=a.x*w0.w+a.y*w1.w+a.z*w2.w+a.w*w3.w;
      a = *(const float4*)(xr2 + k4*4);
      acc[2][0]+=a.x*w0.x+a.y*w1.x+a.z*w2.x+a.w*w3.x; acc[2][1]+=a.x*w0.y+a.y*w1.y+a.z*w2.y+a.w*w3.y;
      acc[2][2]+=a.x*w0.z+a.y*w1.z+a.z*w2.z+a.w*w3.z; acc[2][3]+=a.x*w0.w+a.y*w1.w+a.z*w2.w+a.w*w3.w;
      a = *(const float4*)(xr3 + k4*4);
      acc[3][0]+=a.x*w0.x+a.y*w1.x+a.z*w2.x+a.w*w3.x; acc[3][1]+=a.x*w0.y+a.y*w1.y+a.z*w2.y+a.w*w3.y;
      acc[3][2]+=a.x*w0.z+a.y*w1.z+a.z*w2.z+a.w*w3.z; acc[3][3]+=a.x*w0.w+a.y*w1.w+a.z*w2.w+a.w*w3.w;
    }
    #pragma unroll
    for (int d = 0; d < 4; ++d) {
      hb[(i0+d)*32 + j0+0] = acc[d][0]; hb[(i0+d)*32 + j0+1] = acc[d][1];
      hb[(i0+d)*32 + j0+2] = acc[d][2]; hb[(i0+d)*32 + j0+3] = acc[d][3];
    }
  }
  __syncthreads();

  // phase 3: finalize dinv, reload wbuf (Wm0a | W01 | Wm1a, padded), zero ab
  if (t < K_) dinv[t] = rsqrtf(dinv[t] + 1.0f);
  { int k = t >> 5, j = t & 31;
    wbuf[0    + k*36 + j] = Wm0a[t];
    wbuf[1152 + k*36 + j] = ws[WS_W01 + t];
    wbuf[2304 + k*36 + j] = Wm1a[t]; }
  #pragma unroll
  for (int s = 0; s < 16; ++s) ab[t + s*1024] = 0.f;
  __syncthreads();

  // phase 4: conv0 aggregate (compacted edges, lane-rotated j)
  for (int e = t; e < cnt; e += 1024) {
    uint32_t p = pairs[e];
    int ss = (int)(p & 0xffffu), dd = (int)(p >> 16);
    float c = dinv[ss]*dinv[dd];
    int bs = ss*32, bd = dd*32;
    #pragma unroll
    for (int jj = 0; jj < 32; ++jj) {
      int j = (jj + t) & 31;
      atomicAdd(&ab[bd + j], hb[bs + j]*c);
    }
  }
  __syncthreads();

  // phase 5: c0 = agg + h*dinv^2 + bg0  (in ab)
  #pragma unroll
  for (int s = 0; s < 16; ++s) {
    int o = t + s*1024;
    float dv = dinv[o >> 5];
    ab[o] += hb[o]*dv*dv + bg0[o & 31];
  }
  __syncthreads();

  // phase 6: r0 = relu(c0 @ Wm0a + bm0a) -> hb
  mm32(ab, hb, &wbuf[0], bm0a, true, it, jt);
  __syncthreads();

  // phase 7: meanr0 = mean_rows(r0)
  { int j = t & 31, grp = t >> 5;
    float s = 0.f;
    for (int i = grp*16; i < grp*16 + 16; ++i) s += hb[i*32 + j];
    ab[t] = s; }
  __syncthreads();
  if (t < 32) {
    float s = 0.f;
    #pragma unroll
    for (int q = 0; q < 32; ++q) s += ab[q*32 + t];
    ws[WS_MR0 + (size_t)g*H_ + t] = s * (1.0f/512.0f);
  }
  __syncthreads();

  // phase 8: hnew = r0 @ W01 + b01 -> ab
  mm32(hb, ab, &wbuf[1152], ws + WS_B01, false, it, jt);
  __syncthreads();

  // phase 9: conv1 aggregate into hb
  #pragma unroll
  for (int s = 0; s < 16; ++s) hb[t + s*1024] = 0.f;
  __syncthreads();
  for (int e = t; e < cnt; e += 1024) {
    uint32_t p = pairs[e];
    int ss = (int)(p & 0xffffu), dd = (int)(p >> 16);
    float c = dinv[ss]*dinv[dd];
    int bs = ss*32, bd = dd*32;
    #pragma unroll
    for (int jj = 0; jj < 32; ++jj) {
      int j = (jj + t) & 31;
      atomicAdd(&hb[bd + j], ab[bs + j]*c);
    }
  }
  __syncthreads();

  // phase 10: c1 = agg + hnew*dinv^2 + bg1 (in hb)
  #pragma unroll
  for (int s = 0; s < 16; ++s) {
    int o = t + s*1024;
    float dv = dinv[o >> 5];
    hb[o] += ab[o]*dv*dv + bg1[o & 31];
  }
  __syncthreads();

  // phase 11: r1 = relu(c1 @ Wm1a + bm1a) -> ab
  mm32(hb, ab, &wbuf[2304], bm1a, true, it, jt);
  __syncthreads();

  // phase 12: meanr1
  { int j = t & 31, grp = t >> 5;
    float s = 0.f;
    for (int i = grp*16; i < grp*16 + 16; ++i) s += ab[i*32 + j];
    hb[t] = s; }
  __syncthreads();
  if (t < 32) {
    float s = 0.f;
    #pragma unroll
    for (int q = 0; q < 32; ++q) s += hb[q*32 + t];
    ws[WS_MR1 + (size_t)g*H_ + t] = s * (1.0f/512.0f);
  }
}

// ---------------------------------------------------------------------------
// k4: PI 2x2/stride2 conv + relu, reduced by g0v (chan) & g2v (col) -> Ppi[25]
// ---------------------------------------------------------------------------
__global__ __launch_bounds__(256) void k4_pi(
    const float* __restrict__ PI1, const float* __restrict__ PI2,
    const float* __restrict__ Kc, const float* __restrict__ bc,
    float* __restrict__ ws)
{
  int g = blockIdx.x, br = g >> 6, b = g & 63;
  const float* pig = (br ? PI2 : PI1) + (size_t)b*CF_*P_*P_;
  __shared__ float PIt[CF_*P_*P_];   // 50KB
  __shared__ float KcL[H_*CF_*4];
  __shared__ float bcL[H_], g0L[H_], g2L[PO], ppiL[PO];
  int t = threadIdx.x;
  for (int i = t; i < CF_*P_*P_; i += 256) PIt[i] = pig[i];
  for (int i = t; i < H_*CF_*4; i += 256) KcL[i] = Kc[i];
  if (t < 32) { bcL[t] = bc[t]; g0L[t] = ws[WS_G0V + t]; }
  if (t >= 32 && t < 32+PO) g2L[t-32] = ws[WS_G2V + (t-32)];
  if (t >= 64 && t < 64+PO) ppiL[t-64] = 0.f;
  __syncthreads();
  for (int e = t; e < H_*PO*PO; e += 256) {
    int i = e / (PO*PO);
    int r = e - i*(PO*PO);
    int jp = r / PO, kp = r - jp*PO;
    float acc = bcL[i];
    const float* kcp = &KcL[i*20];
    #pragma unroll
    for (int c = 0; c < CF_; ++c) {
      const float* pp = &PIt[c*2500 + (2*jp)*50 + 2*kp];
      acc += pp[0]*kcp[c*4+0] + pp[1]*kcp[c*4+1] + pp[50]*kcp[c*4+2] + pp[51]*kcp[c*4+3];
    }
    float v = fmaxf(acc, 0.f) * g0L[i] * g2L[kp];
    atomicAdd(&ppiL[jp], v);
  }
  __syncthreads();
  if (t < PO) ws[WS_PPI + (size_t)g*PO + t] = ppiL[t];
}

// ---------------------------------------------------------------------------
// k5: per-graph tail: m1/m2 via Wm0b/Wm1b, folded tcl chain, output head
// ---------------------------------------------------------------------------
__global__ __launch_bounds__(256) void k5_final(
    const float* __restrict__ Wm0b, const float* __restrict__ bm0b,
    const float* __restrict__ Wm1b, const float* __restrict__ bm1b,
    const float* __restrict__ F1w, const float* __restrict__ G1w,
    const float* __restrict__ H1w, const float* __restrict__ Wo1,
    const float* __restrict__ bo1, const float* __restrict__ Wo2,
    const float* __restrict__ bo2, const float* __restrict__ ws,
    float* __restrict__ out)
{
  int g = blockIdx.x, t = threadIdx.x;
  __shared__ float m1L[1024], m2L[1024];
  __shared__ float mr0[32], mr1[32], AL[32], TL[32], pl[32], zl[32], ppi[PO];
  if (t < 32) { mr0[t] = ws[WS_MR0 + (size_t)g*H_ + t]; mr1[t] = ws[WS_MR1 + (size_t)g*H_ + t]; }
  if (t >= 32 && t < 32+PO) ppi[t-32] = ws[WS_PPI + (size_t)g*PO + (t-32)];
  __syncthreads();
  #pragma unroll
  for (int s = 0; s < 4; ++s) {
    int cc = t + s*256;
    float a1 = bm0b[cc], a2 = bm1b[cc];
    for (int k = 0; k < 32; ++k) {
      a1 += mr0[k]*Wm0b[k*1024 + cc];
      a2 += mr1[k]*Wm1b[k*1024 + cc];
    }
    m1L[cc] = a1; m2L[cc] = a2;
  }
  __syncthreads();
  float f00 = ws[WS_F0V], f01 = ws[WS_F0V+1];
  if (t < 32) {
    float s = 0.f;
    for (int kp = 0; kp < 32; ++kp)
      s += ws[WS_F2V + kp] * (f00*m1L[t*32+kp] + f01*m2L[t*32+kp]);
    AL[t] = s;
  }
  __syncthreads();
  if (t < 32) {
    float s = 0.f;
    for (int jp = 0; jp < 32; ++jp) s += F1w[t*32+jp]*AL[jp];
    for (int jp = 0; jp < PO; ++jp) s += G1w[t*25+jp]*ppi[jp];
    TL[t] = s;
  }
  __syncthreads();
  if (t < 32) {
    float s = 0.f;
    for (int j = 0; j < 32; ++j) s += H1w[t*32+j]*TL[j];
    pl[t] = s;
  }
  __syncthreads();
  if (t < 32) {
    float s = bo1[t];
    for (int j = 0; j < 32; ++j) s += pl[j]*Wo1[j*32+t];
    zl[t] = fmaxf(s, 0.f);
  }
  __syncthreads();
  if (t < 2) {
    float s = bo2[t];
    for (int q = 0; q < 32; ++q) s += zl[q]*Wo2[q*2+t];
    int br = g >> 6, b = g & 63;
    out[br*(B_*2) + b*2 + t] = s;
  }
}

// ---------------------------------------------------------------------------
extern "C" void kernel_launch(void* const* d_in, const int* in_sizes, int n_in,
                              void* d_out, int out_size, void* d_ws, size_t ws_size,
                              hipStream_t stream) {
  (void)in_sizes; (void)n_in; (void)out_size; (void)ws_size;
  const float* x1      = (const float*)d_in[0];
  const int*   ei1     = (const int*)  d_in[1];
  const float* PI1     = (const float*)d_in[2];
  const float* x2      = (const float*)d_in[3];
  const int*   ei2     = (const int*)  d_in[4];
  const float* PI2     = (const float*)d_in[5];
  const float* W_score = (const float*)d_in[6];
  const float* b_score = (const float*)d_in[7];
  const float* W_gcn0  = (const float*)d_in[8];
  const float* b_gcn0  = (const float*)d_in[9];
  const float* Wm0a    = (const float*)d_in[10];
  const float* bm0a    = (const float*)d_in[11];
  const float* Wm0b    = (const float*)d_in[12];
  const float* bm0b    = (const float*)d_in[13];
  const float* W_gcn1  = (const float*)d_in[14];
  const float* b_gcn1  = (const float*)d_in[15];
  const float* Wm1a    = (const float*)d_in[16];
  const float* bm1a    = (const float*)d_in[17];
  const float* Wm1b    = (const float*)d_in[18];
  const float* bm1b    = (const float*)d_in[19];
  const float* F0w     = (const float*)d_in[20];
  const float* F1w     = (const float*)d_in[21];
  const float* F2w     = (const float*)d_in[22];
  const float* Kc      = (const float*)d_in[23];
  const float* bc      = (const float*)d_in[24];
  const float* G0w     = (const float*)d_in[25];
  const float* G1w     = (const float*)d_in[26];
  const float* G2w     = (const float*)d_in[27];
  const float* H0w     = (const float*)d_in[28];
  const float* H1w     = (const float*)d_in[29];
  const float* H2w     = (const float*)d_in[30];
  const float* Wo1     = (const float*)d_in[31];
  const float* bo1     = (const float*)d_in[32];
  const float* Wo2     = (const float*)d_in[33];
  const float* bo2     = (const float*)d_in[34];
  float* ws  = (float*)d_ws;
  float* out = (float*)d_out;

  k0_setup<<<5, 256, 0, stream>>>(F0w, F2w, G0w, G2w, H0w, H2w, Wm0b, bm0b, W_gcn1, ws);
  k1_scorefeat<<<dim3(G_, 4), 256, 0, stream>>>(x1, x2, W_score, ws);
  k2_pool<<<G_, 1024, 0, stream>>>(ei1, ei2, b_score, ws);
  k3_graph<<<G_, 1024, 0, stream>>>(x1, x2, ei1, ei2, W_gcn0, b_gcn0, Wm0a, bm0a,
                                    b_gcn1, Wm1a, bm1a, ws);
  k4_pi<<<G_, 256, 0, stream>>>(PI1, PI2, Kc, bc, ws);
  k5_final<<<G_, 256, 0, stream>>>(Wm0b, bm0b, Wm1b, bm1b, F1w, G1w, H1w,
                                   Wo1, bo1, Wo2, bo2, ws, out);
}

// Round 2
// 304.682 us; speedup vs baseline: 4.4979x; 4.4979x over previous
//
#include <hip/hip_runtime.h>
#include <cstdint>

// ---------------------------------------------------------------------------
// TenGCN fused forward, atomic-free rewrite.
// 128 graphs (2 branches x 64 batches). All scatter-adds converted to gathers
// over a per-graph dst-sorted CSR (kcsr). No float atomics anywhere.
// h1/h2 eliminated via W01 = Wm0b @ W_gcn1; tcl chain folded (k0).
// ---------------------------------------------------------------------------

constexpr int B_ = 64, N_ = 1024, E_ = 32768, F_ = 128, H_ = 32;
constexpr int CF_ = 5, P_ = 50, K_ = 512, G_ = 128, PO = 25;

// workspace offsets (in 4-byte units)
constexpr size_t WS_NIDX  = 0;                                // G*N ints
constexpr size_t WS_OFF   = WS_NIDX + (size_t)G_*N_;          // G*1025 ints
constexpr size_t WS_SRCS  = WS_OFF + (size_t)G_*1025;         // G*E u16 -> G*16384 slots
constexpr size_t WS_MR0   = WS_SRCS + (size_t)G_*(E_/2);      // G*32
constexpr size_t WS_MR1   = WS_MR0 + (size_t)G_*H_;           // G*32
constexpr size_t WS_PPI   = WS_MR1 + (size_t)G_*H_;           // G*25
constexpr size_t WS_H0M   = WS_PPI + (size_t)G_*PO;           // 64
constexpr size_t WS_H2M   = WS_H0M + 64;                      // 32
constexpr size_t WS_F0V   = WS_H2M + 32;                      // 2
constexpr size_t WS_F2V   = WS_F0V + 2;                       // 32
constexpr size_t WS_G0V   = WS_F2V + 32;                      // 32
constexpr size_t WS_G2V   = WS_G0V + 32;                      // 25 (pad 32)
constexpr size_t WS_B01   = WS_G2V + 32;                      // 32
constexpr size_t WS_W01   = WS_B01 + 32;                      // 1024

// swizzled column group: logical col j of row r lives at
// r*32 + (((j>>2) ^ ((r>>2)&7))<<2) + (j&3)
static __device__ __forceinline__ int swzf4(int row, int c4) {
  return row*32 + (((c4) ^ ((row >> 2) & 7)) << 2);
}

// ---------------------------------------------------------------------------
// kcsr: per-graph counting sort of edges by dst. int atomics only.
// ---------------------------------------------------------------------------
__global__ __launch_bounds__(1024) void kcsr(
    const int* __restrict__ ei1, const int* __restrict__ ei2,
    float* __restrict__ ws)
{
  int g = blockIdx.x, br = g >> 6, b = g & 63;
  const int* ei  = (br ? ei2 : ei1) + (size_t)b*2*E_;
  const int* src = ei;
  const int* dst = ei + E_;
  int* offg = (int*)ws + WS_OFF + (size_t)g*1025;
  uint16_t* srcSg = (uint16_t*)(ws + WS_SRCS) + (size_t)g*E_;

  __shared__ uint16_t dstL[E_];   // 64KB
  __shared__ uint16_t srcL[E_];   // 64KB
  __shared__ int cnt[N_], fill[N_], offL[N_], sa[N_], sb[N_];

  int t = threadIdx.x;
  cnt[t] = 0; fill[t] = 0;
  __syncthreads();
  for (int e = t; e < E_; e += 1024) {
    int d = dst[e];
    dstL[e] = (uint16_t)d;
    atomicAdd(&cnt[d], 1);
  }
  __syncthreads();
  // Hillis-Steele inclusive scan over 1024 counts
  sa[t] = cnt[t];
  __syncthreads();
  int* cur = sa; int* nxt = sb;
  for (int s = 1; s < N_; s <<= 1) {
    int v = cur[t] + (t >= s ? cur[t - s] : 0);
    nxt[t] = v;
    __syncthreads();
    int* tmp = cur; cur = nxt; nxt = tmp;
  }
  int excl = cur[t] - cnt[t];
  offL[t] = excl;
  offg[t] = excl;
  if (t == 0) offg[N_] = E_;
  __syncthreads();
  for (int e = t; e < E_; e += 1024) {
    int d = dstL[e];
    int pos = offL[d] + atomicAdd(&fill[d], 1);
    srcL[pos] = (uint16_t)src[e];
  }
  __syncthreads();
  { const uint4* si = (const uint4*)srcL;
    uint4* so = (uint4*)srcSg;
    for (int i = t; i < E_*2/16; i += 1024) so[i] = si[i]; }
}

// ---------------------------------------------------------------------------
// k0: tiny precomputations (unchanged math, new offsets).
// ---------------------------------------------------------------------------
__global__ __launch_bounds__(256) void k0_setup(
    const float* __restrict__ F0w, const float* __restrict__ F2w,
    const float* __restrict__ G0w, const float* __restrict__ G2w,
    const float* __restrict__ H0w, const float* __restrict__ H2w,
    const float* __restrict__ Wm0b, const float* __restrict__ bm0b,
    const float* __restrict__ Wg1, float* __restrict__ ws)
{
  int t = threadIdx.x;
  if (blockIdx.x == 0) {
    __shared__ float h0m[64], h2m[32];
    if (t < 64) { float s = 0.f; for (int p = 0; p < 64; ++p) s += H0w[p*64+t]; h0m[t] = s*(1.f/64.f); }
    if (t < 32) { float s = 0.f; for (int r = 0; r < 32; ++r) s += H2w[r*32+t]; h2m[t] = s*(1.f/32.f); }
    __syncthreads();
    if (t < 64) ws[WS_H0M+t] = h0m[t];
    if (t < 32) ws[WS_H2M+t] = h2m[t];
    if (t < 2)  { float s=0.f; for (int p=0;p<32;++p) s += F0w[p*2+t]*h0m[p];     ws[WS_F0V+t]=s; }
    if (t < 32) { float s=0.f; for (int r=0;r<32;++r) s += F2w[r*32+t]*h2m[r];    ws[WS_F2V+t]=s; }
    if (t < 32) { float s=0.f; for (int p=0;p<32;++p) s += G0w[p*32+t]*h0m[32+p]; ws[WS_G0V+t]=s; }
    if (t < PO) { float s=0.f; for (int r=0;r<32;++r) s += G2w[r*25+t]*h2m[r];    ws[WS_G2V+t]=s; }
    if (t < 32) { float s=0.f; for (int k=0;k<1024;++k) s += bm0b[k]*Wg1[k*32+t]; ws[WS_B01+t]=s; }
  } else {
    int o = (blockIdx.x-1)*256 + t;       // 0..1023
    int kk = o >> 5, j = o & 31;
    float s = 0.f;
    for (int tt = 0; tt < 1024; ++tt) s += Wm0b[kk*1024+tt]*Wg1[tt*32+j];
    ws[WS_W01+o] = s;
  }
}

// ---------------------------------------------------------------------------
// k2: score features (x@W_score), scoring GCN via CSR gather, top-512.
// One WG of 1024 threads per graph, ~69KB LDS (2 blocks/CU).
// ---------------------------------------------------------------------------
__global__ __launch_bounds__(1024) void k2_pool(
    const float* __restrict__ x1, const float* __restrict__ x2,
    const float* __restrict__ Wsc, const float* __restrict__ bsc,
    float* __restrict__ ws)
{
  int g = blockIdx.x, br = g >> 6, b = g & 63;
  const float* xg = (br ? x2 : x1) + (size_t)b*N_*F_;
  const int* offg = (const int*)ws + WS_OFF + (size_t)g*1025;
  const uint16_t* srcS = (const uint16_t*)(ws + WS_SRCS) + (size_t)g*E_;

  __shared__ float Ws[F_*10];       // 5KB
  __shared__ float hsd[N_*12];      // 48KB (row-padded to 12, pre-scaled by dinv)
  __shared__ float dinvL[N_];
  __shared__ float keyL[N_];
  __shared__ int   idxL[N_];
  __shared__ int   nidxL[N_];

  int t = threadIdx.x;
  for (int i = t; i < F_*10; i += 1024) Ws[i] = Wsc[i];
  int off0 = offg[t], off1 = offg[t+1];
  float dv = rsqrtf((float)(off1 - off0) + 1.0f);
  dinvL[t] = dv;
  __syncthreads();

  // hs row for node t: x[t] @ W_score, pre-scaled by dinv[t]
  {
    const float4* xr = (const float4*)(xg + (size_t)t*F_);
    float acc[10] = {};
    for (int k4 = 0; k4 < 32; ++k4) {
      float4 v = xr[k4];
      const float* w = &Ws[k4*40];
      #pragma unroll
      for (int j = 0; j < 10; ++j)
        acc[j] += v.x*w[j] + v.y*w[10+j] + v.z*w[20+j] + v.w*w[30+j];
    }
    #pragma unroll
    for (int j = 0; j < 10; ++j) hsd[t*12+j] = acc[j]*dv;
  }
  __syncthreads();

  // gather over in-edges of node t
  {
    float agg[10] = {};
    for (int e = off0; e < off1; ++e) {
      int s = srcS[e];
      const float* hr = &hsd[s*12];
      float4 a0 = *(const float4*)hr;
      float4 a1 = *(const float4*)(hr+4);
      float2 a2 = *(const float2*)(hr+8);
      agg[0]+=a0.x; agg[1]+=a0.y; agg[2]+=a0.z; agg[3]+=a0.w;
      agg[4]+=a1.x; agg[5]+=a1.y; agg[6]+=a1.z; agg[7]+=a1.w;
      agg[8]+=a2.x; agg[9]+=a2.y;
    }
    float sc = 0.f;
    #pragma unroll
    for (int j = 0; j < 5; ++j) {
      float e0 = dv*(agg[2*j]   + hsd[t*12+2*j])   + bsc[2*j];
      float e1 = dv*(agg[2*j+1] + hsd[t*12+2*j+1]) + bsc[2*j+1];
      sc += fabsf(e1 - e0);
    }
    keyL[t] = sc; idxL[t] = t;
  }
  __syncthreads();

  // bitonic sort: (score desc, idx asc)
  for (int k = 2; k <= N_; k <<= 1) {
    for (int j = k >> 1; j > 0; j >>= 1) {
      int ixj = t ^ j;
      if (ixj > t) {
        float ka = keyL[t], kb = keyL[ixj];
        int   ia = idxL[t], ib = idxL[ixj];
        bool aAfter = (ka < kb) || (ka == kb && ia > ib);
        bool doSwap = ((t & k) == 0) ? aAfter : !aAfter;
        if (doSwap) { keyL[t]=kb; keyL[ixj]=ka; idxL[t]=ib; idxL[ixj]=ia; }
      }
      __syncthreads();
    }
  }
  nidxL[t] = -1;
  __syncthreads();
  if (t < K_) nidxL[idxL[t]] = t;
  __syncthreads();
  ((int*)ws)[WS_NIDX + (size_t)g*N_ + t] = nidxL[t];
}

// ---------------------------------------------------------------------------
// 512x32 @ 32x32 matmul on swizzled LDS buffers. W padded [32][36].
// A-reads: group kv^ (it&7) -> 8 distinct groups, conflict-free.
// W-reads: all lanes same row, 8 j-groups -> conflict-free.
// ---------------------------------------------------------------------------
static __device__ __forceinline__ void mm32(
    const float* __restrict__ S, float* __restrict__ D,
    const float* __restrict__ Wp, const float* __restrict__ bias,
    const float* __restrict__ rowscale, bool do_relu, int t)
{
  const int it = t >> 3, jt = t & 7;
  const int i0 = it*4;
  const int swa = it & 7;
  float acc[4][4] = {};
  #pragma unroll
  for (int kv = 0; kv < 8; ++kv) {
    float4 w0 = *(const float4*)&Wp[(kv*4+0)*36 + jt*4];
    float4 w1 = *(const float4*)&Wp[(kv*4+1)*36 + jt*4];
    float4 w2 = *(const float4*)&Wp[(kv*4+2)*36 + jt*4];
    float4 w3 = *(const float4*)&Wp[(kv*4+3)*36 + jt*4];
    #pragma unroll
    for (int d = 0; d < 4; ++d) {
      float4 a = *(const float4*)&S[(i0+d)*32 + ((kv ^ swa) << 2)];
      acc[d][0] += a.x*w0.x + a.y*w1.x + a.z*w2.x + a.w*w3.x;
      acc[d][1] += a.x*w0.y + a.y*w1.y + a.z*w2.y + a.w*w3.y;
      acc[d][2] += a.x*w0.z + a.y*w1.z + a.z*w2.z + a.w*w3.z;
      acc[d][3] += a.x*w0.w + a.y*w1.w + a.z*w2.w + a.w*w3.w;
    }
  }
  float b0 = bias[jt*4+0], b1 = bias[jt*4+1], b2 = bias[jt*4+2], b3 = bias[jt*4+3];
  #pragma unroll
  for (int d = 0; d < 4; ++d) {
    int row = i0 + d;
    float v0 = acc[d][0]+b0, v1 = acc[d][1]+b1, v2 = acc[d][2]+b2, v3 = acc[d][3]+b3;
    if (do_relu) { v0=fmaxf(v0,0.f); v1=fmaxf(v1,0.f); v2=fmaxf(v2,0.f); v3=fmaxf(v3,0.f); }
    if (rowscale) { float rs = rowscale[row]; v0*=rs; v1*=rs; v2*=rs; v3*=rs; }
    float4 o; o.x=v0; o.y=v1; o.z=v2; o.w=v3;
    *(float4*)&D[row*32 + ((jt ^ swa) << 2)] = o;
  }
}

// ---------------------------------------------------------------------------
// gather conv: D[dd] = dinv[dd]*(sum_{valid in-edges} S[ss] + S[dd]) + bias
// thread = (dd = t&511, half = t>>9), 16 features each. No atomics.
// ---------------------------------------------------------------------------
static __device__ __forceinline__ void gatherconv(
    const float* __restrict__ S, float* __restrict__ D,
    const float* __restrict__ bias,
    const float* __restrict__ dinv, const int* __restrict__ nidx,
    const int* __restrict__ onode, const int* __restrict__ offg,
    const uint16_t* __restrict__ srcS, int t)
{
  int dd = t & 511, half = t >> 9;
  int o = onode[dd];
  int lo = offg[o], hi = offg[o+1];
  int c0g = half*4;     // logical col groups c0g..c0g+3
  float4 a0 = {0,0,0,0}, a1 = a0, a2 = a0, a3 = a0;
  for (int e = lo; e < hi; ++e) {
    int ss = nidx[srcS[e]];
    if (ss >= 0) {
      float4 v;
      v = *(const float4*)&S[swzf4(ss, c0g+0)]; a0.x+=v.x; a0.y+=v.y; a0.z+=v.z; a0.w+=v.w;
      v = *(const float4*)&S[swzf4(ss, c0g+1)]; a1.x+=v.x; a1.y+=v.y; a1.z+=v.z; a1.w+=v.w;
      v = *(const float4*)&S[swzf4(ss, c0g+2)]; a2.x+=v.x; a2.y+=v.y; a2.z+=v.z; a2.w+=v.w;
      v = *(const float4*)&S[swzf4(ss, c0g+3)]; a3.x+=v.x; a3.y+=v.y; a3.z+=v.z; a3.w+=v.w;
    }
  }
  float dvd = dinv[dd];
  float4 s0 = *(const float4*)&S[swzf4(dd, c0g+0)];
  float4 s1 = *(const float4*)&S[swzf4(dd, c0g+1)];
  float4 s2 = *(const float4*)&S[swzf4(dd, c0g+2)];
  float4 s3 = *(const float4*)&S[swzf4(dd, c0g+3)];
  int cb = half*16;
  float4 r0, r1, r2, r3;
  r0.x = dvd*(a0.x+s0.x) + bias[cb+0];  r0.y = dvd*(a0.y+s0.y) + bias[cb+1];
  r0.z = dvd*(a0.z+s0.z) + bias[cb+2];  r0.w = dvd*(a0.w+s0.w) + bias[cb+3];
  r1.x = dvd*(a1.x+s1.x) + bias[cb+4];  r1.y = dvd*(a1.y+s1.y) + bias[cb+5];
  r1.z = dvd*(a1.z+s1.z) + bias[cb+6];  r1.w = dvd*(a1.w+s1.w) + bias[cb+7];
  r2.x = dvd*(a2.x+s2.x) + bias[cb+8];  r2.y = dvd*(a2.y+s2.y) + bias[cb+9];
  r2.z = dvd*(a2.z+s2.z) + bias[cb+10]; r2.w = dvd*(a2.w+s2.w) + bias[cb+11];
  r3.x = dvd*(a3.x+s3.x) + bias[cb+12]; r3.y = dvd*(a3.y+s3.y) + bias[cb+13];
  r3.z = dvd*(a3.z+s3.z) + bias[cb+14]; r3.w = dvd*(a3.w+s3.w) + bias[cb+15];
  *(float4*)&D[swzf4(dd, c0g+0)] = r0;
  *(float4*)&D[swzf4(dd, c0g+1)] = r1;
  *(float4*)&D[swzf4(dd, c0g+2)] = r2;
  *(float4*)&D[swzf4(dd, c0g+3)] = r3;
}

// ---------------------------------------------------------------------------
// k3: pooled per-graph pipeline, atomic-free.
// ---------------------------------------------------------------------------
__global__ __launch_bounds__(1024) void k3_graph(
    const float* __restrict__ x1, const float* __restrict__ x2,
    const float* __restrict__ Wg0, const float* __restrict__ bg0,
    const float* __restrict__ Wm0a, const float* __restrict__ bm0a,
    const float* __restrict__ bg1, const float* __restrict__ Wm1a,
    const float* __restrict__ bm1a, float* __restrict__ ws)
{
  int g = blockIdx.x, br = g >> 6, b = g & 63;
  const float* xg = (br ? x2 : x1) + (size_t)b*N_*F_;
  const int* nidxg = (const int*)ws + WS_NIDX + (size_t)g*N_;
  const int* offg  = (const int*)ws + WS_OFF + (size_t)g*1025;
  const uint16_t* srcS = (const uint16_t*)(ws + WS_SRCS) + (size_t)g*E_;

  __shared__ float bufA[K_*H_];   // 64KB
  __shared__ float bufB[K_*H_];   // 64KB
  __shared__ float wbuf[F_*36];   // 18KB
  __shared__ float dinv[K_];      // 2KB
  __shared__ int   nidx[N_];      // 4KB
  __shared__ int   onode[K_];     // 2KB

  const int t = threadIdx.x;

  // P0: loads
  nidx[t] = nidxg[t];
  for (int i = t; i < F_*H_; i += 1024) wbuf[(i >> 5)*36 + (i & 31)] = Wg0[i];
  __syncthreads();
  { int ii = nidx[t]; if (ii >= 0) onode[ii] = t; }
  __syncthreads();

  // P1: valid in-degree -> dinv (thread-pair per node, shfl combine)
  {
    int dd = t >> 1, hh = t & 1;
    int o = onode[dd];
    int lo = offg[o], hi = offg[o+1];
    int mid = lo + ((hi - lo) >> 1);
    int a = hh ? mid : lo, bnd = hh ? hi : mid;
    int c = 0;
    for (int e = a; e < bnd; ++e) c += (nidx[srcS[e]] >= 0) ? 1 : 0;
    c += __shfl_xor(c, 1);
    if (!hh) dinv[dd] = rsqrtf((float)c + 1.0f);
  }
  __syncthreads();

  // P2: bufA = rowscale(X[onode] @ Wg0)  (hb2)
  {
    const int it = t >> 3, jt = t & 7;
    const int i0 = it*4;
    const float* xr0 = xg + (size_t)onode[i0+0]*F_;
    const float* xr1 = xg + (size_t)onode[i0+1]*F_;
    const float* xr2 = xg + (size_t)onode[i0+2]*F_;
    const float* xr3 = xg + (size_t)onode[i0+3]*F_;
    float acc[4][4] = {};
    for (int k4 = 0; k4 < 32; ++k4) {
      float4 w0 = *(const float4*)&wbuf[(k4*4+0)*36 + jt*4];
      float4 w1 = *(const float4*)&wbuf[(k4*4+1)*36 + jt*4];
      float4 w2 = *(const float4*)&wbuf[(k4*4+2)*36 + jt*4];
      float4 w3 = *(const float4*)&wbuf[(k4*4+3)*36 + jt*4];
      float4 a;
      a = *(const float4*)(xr0 + k4*4);
      acc[0][0]+=a.x*w0.x+a.y*w1.x+a.z*w2.x+a.w*w3.x; acc[0][1]+=a.x*w0.y+a.y*w1.y+a.z*w2.y+a.w*w3.y;
      acc[0][2]+=a.x*w0.z+a.y*w1.z+a.z*w2.z+a.w*w3.z; acc[0][3]+=a.x*w0.w+a.y*w1.w+a.z*w2.w+a.w*w3.w;
      a = *(const float4*)(xr1 + k4*4);
      acc[1][0]+=a.x*w0.x+a.y*w1.x+a.z*w2.x+a.w*w3.x; acc[1][1]+=a.x*w0.y+a.y*w1.y+a.z*w2.y+a.w*w3.y;
      acc[1][2]+=a.x*w0.z+a.y*w1.z+a.z*w2.z+a.w*w3.z; acc[1][3]+=a.x*w0.w+a.y*w1.w+a.z*w2.w+a.w*w3.w;
      a = *(const float4*)(xr2 + k4*4);
      acc[2][0]+=a.x*w0.x+a.y*w1.x+a.z*w2.x+a.w*w3.x; acc[2][1]+=a.x*w0.y+a.y*w1.y+a.z*w2.y+a.w*w3.y;
      acc[2][2]+=a.x*w0.z+a.y*w1.z+a.z*w2.z+a.w*w3.z; acc[2][3]+=a.x*w0.w+a.y*w1.w+a.z*w2.w+a.w*w3.w;
      a = *(const float4*)(xr3 + k4*4);
      acc[3][0]+=a.x*w0.x+a.y*w1.x+a.z*w2.x+a.w*w3.x; acc[3][1]+=a.x*w0.y+a.y*w1.y+a.z*w2.y+a.w*w3.y;
      acc[3][2]+=a.x*w0.z+a.y*w1.z+a.z*w2.z+a.w*w3.z; acc[3][3]+=a.x*w0.w+a.y*w1.w+a.z*w2.w+a.w*w3.w;
    }
    #pragma unroll
    for (int d = 0; d < 4; ++d) {
      int row = i0 + d;
      float rs = dinv[row];
      float4 o; o.x=acc[d][0]*rs; o.y=acc[d][1]*rs; o.z=acc[d][2]*rs; o.w=acc[d][3]*rs;
      *(float4*)&bufA[row*32 + ((jt ^ (it & 7)) << 2)] = o;
    }
  }
  __syncthreads();

  // P3: small weights into wbuf (Wm0a | W01 | Wm1a), [32][36] each
  { int k = t >> 5, j = t & 31;
    wbuf[0    + k*36 + j] = Wm0a[t];
    wbuf[1152 + k*36 + j] = ws[WS_W01 + t];
    wbuf[2304 + k*36 + j] = Wm1a[t]; }
  __syncthreads();

  // P4: conv0 gather: bufB = c0
  gatherconv(bufA, bufB, bg0, dinv, nidx, onode, offg, srcS, t);
  __syncthreads();

  // P6: r0 = relu(c0 @ Wm0a + bm0a) -> bufA
  mm32(bufB, bufA, &wbuf[0], bm0a, nullptr, true, t);
  __syncthreads();

  // P7: meanr0 (scratch = bufB[0..1023])
  { int j = t & 31, grp = t >> 5;
    float s = 0.f;
    for (int i = grp*16; i < grp*16 + 16; ++i)
      s += bufA[i*32 + ((((j >> 2) ^ ((i >> 2) & 7)) << 2) | (j & 3))];
    bufB[t] = s; }
  __syncthreads();
  if (t < 32) {
    float s = 0.f;
    #pragma unroll
    for (int q = 0; q < 32; ++q) s += bufB[q*32 + t];
    ws[WS_MR0 + (size_t)g*H_ + t] = s * (1.0f/512.0f);
  }
  __syncthreads();

  // P8: hnew2 = (r0 @ W01 + b01) * dinv -> bufB
  mm32(bufA, bufB, &wbuf[1152], ws + WS_B01, dinv, false, t);
  __syncthreads();

  // P9: conv1 gather: bufA = c1
  gatherconv(bufB, bufA, bg1, dinv, nidx, onode, offg, srcS, t);
  __syncthreads();

  // P11: r1 = relu(c1 @ Wm1a + bm1a) -> bufB
  mm32(bufA, bufB, &wbuf[2304], bm1a, nullptr, true, t);
  __syncthreads();

  // P12: meanr1 (scratch = bufA[0..1023])
  { int j = t & 31, grp = t >> 5;
    float s = 0.f;
    for (int i = grp*16; i < grp*16 + 16; ++i)
      s += bufB[i*32 + ((((j >> 2) ^ ((i >> 2) & 7)) << 2) | (j & 3))];
    bufA[t] = s; }
  __syncthreads();
  if (t < 32) {
    float s = 0.f;
    #pragma unroll
    for (int q = 0; q < 32; ++q) s += bufA[q*32 + t];
    ws[WS_MR1 + (size_t)g*H_ + t] = s * (1.0f/512.0f);
  }
}

// ---------------------------------------------------------------------------
// k4: PI conv + relu, reduced by g0v/g2v. No atomics: thread=(jp,sub) + shfl.
// ---------------------------------------------------------------------------
__global__ __launch_bounds__(256) void k4_pi(
    const float* __restrict__ PI1, const float* __restrict__ PI2,
    const float* __restrict__ Kc, const float* __restrict__ bc,
    float* __restrict__ ws)
{
  int g = blockIdx.x, br = g >> 6, b = g & 63;
  const float* pig = (br ? PI2 : PI1) + (size_t)b*CF_*P_*P_;
  __shared__ float PIt[CF_*P_*P_];   // 50KB
  __shared__ float KcL[H_*CF_*4];
  __shared__ float bcL[H_], g0L[H_], g2L[PO];
  int t = threadIdx.x;
  for (int i = t; i < CF_*P_*P_; i += 256) PIt[i] = pig[i];
  for (int i = t; i < H_*CF_*4; i += 256) KcL[i] = Kc[i];
  if (t < 32) { bcL[t] = bc[t]; g0L[t] = ws[WS_G0V + t]; }
  if (t >= 32 && t < 32+PO) g2L[t-32] = ws[WS_G2V + (t-32)];
  __syncthreads();
  int jp = t >> 3, sub = t & 7;
  float acc = 0.f;
  if (jp < PO) {
    for (int i = sub; i < H_; i += 8) {
      const float* kcp = &KcL[i*20];
      float bi = bcL[i], gi = g0L[i];
      for (int kp = 0; kp < PO; ++kp) {
        float v = bi;
        #pragma unroll
        for (int c = 0; c < CF_; ++c) {
          const float* pp = &PIt[c*2500 + (2*jp)*50 + 2*kp];
          v += pp[0]*kcp[c*4+0] + pp[1]*kcp[c*4+1] + pp[50]*kcp[c*4+2] + pp[51]*kcp[c*4+3];
        }
        acc += fmaxf(v, 0.f) * gi * g2L[kp];
      }
    }
  }
  #pragma unroll
  for (int d = 4; d > 0; d >>= 1) acc += __shfl_down(acc, d, 8);
  if (sub == 0 && jp < PO) ws[WS_PPI + (size_t)g*PO + jp] = acc;
}

// ---------------------------------------------------------------------------
// k5: per-graph tail (unchanged math).
// ---------------------------------------------------------------------------
__global__ __launch_bounds__(256) void k5_final(
    const float* __restrict__ Wm0b, const float* __restrict__ bm0b,
    const float* __restrict__ Wm1b, const float* __restrict__ bm1b,
    const float* __restrict__ F1w, const float* __restrict__ G1w,
    const float* __restrict__ H1w, const float* __restrict__ Wo1,
    const float* __restrict__ bo1, const float* __restrict__ Wo2,
    const float* __restrict__ bo2, const float* __restrict__ ws,
    float* __restrict__ out)
{
  int g = blockIdx.x, t = threadIdx.x;
  __shared__ float m1L[1024], m2L[1024];
  __shared__ float mr0[32], mr1[32], AL[32], TL[32], pl[32], zl[32], ppi[PO];
  if (t < 32) { mr0[t] = ws[WS_MR0 + (size_t)g*H_ + t]; mr1[t] = ws[WS_MR1 + (size_t)g*H_ + t]; }
  if (t >= 32 && t < 32+PO) ppi[t-32] = ws[WS_PPI + (size_t)g*PO + (t-32)];
  __syncthreads();
  #pragma unroll
  for (int s = 0; s < 4; ++s) {
    int cc = t + s*256;
    float a1 = bm0b[cc], a2 = bm1b[cc];
    for (int k = 0; k < 32; ++k) {
      a1 += mr0[k]*Wm0b[k*1024 + cc];
      a2 += mr1[k]*Wm1b[k*1024 + cc];
    }
    m1L[cc] = a1; m2L[cc] = a2;
  }
  __syncthreads();
  float f00 = ws[WS_F0V], f01 = ws[WS_F0V+1];
  if (t < 32) {
    float s = 0.f;
    for (int kp = 0; kp < 32; ++kp)
      s += ws[WS_F2V + kp] * (f00*m1L[t*32+kp] + f01*m2L[t*32+kp]);
    AL[t] = s;
  }
  __syncthreads();
  if (t < 32) {
    float s = 0.f;
    for (int jp = 0; jp < 32; ++jp) s += F1w[t*32+jp]*AL[jp];
    for (int jp = 0; jp < PO; ++jp) s += G1w[t*25+jp]*ppi[jp];
    TL[t] = s;
  }
  __syncthreads();
  if (t < 32) {
    float s = 0.f;
    for (int j = 0; j < 32; ++j) s += H1w[t*32+j]*TL[j];
    pl[t] = s;
  }
  __syncthreads();
  if (t < 32) {
    float s = bo1[t];
    for (int j = 0; j < 32; ++j) s += pl[j]*Wo1[j*32+t];
    zl[t] = fmaxf(s, 0.f);
  }
  __syncthreads();
  if (t < 2) {
    float s = bo2[t];
    for (int q = 0; q < 32; ++q) s += zl[q]*Wo2[q*2+t];
    int br = g >> 6, b = g & 63;
    out[br*(B_*2) + b*2 + t] = s;
  }
}

// ---------------------------------------------------------------------------
extern "C" void kernel_launch(void* const* d_in, const int* in_sizes, int n_in,
                              void* d_out, int out_size, void* d_ws, size_t ws_size,
                              hipStream_t stream) {
  (void)in_sizes; (void)n_in; (void)out_size; (void)ws_size;
  const float* x1      = (const float*)d_in[0];
  const int*   ei1     = (const int*)  d_in[1];
  const float* PI1     = (const float*)d_in[2];
  const float* x2      = (const float*)d_in[3];
  const int*   ei2     = (const int*)  d_in[4];
  const float* PI2     = (const float*)d_in[5];
  const float* W_score = (const float*)d_in[6];
  const float* b_score = (const float*)d_in[7];
  const float* W_gcn0  = (const float*)d_in[8];
  const float* b_gcn0  = (const float*)d_in[9];
  const float* Wm0a    = (const float*)d_in[10];
  const float* bm0a    = (const float*)d_in[11];
  const float* Wm0b    = (const float*)d_in[12];
  const float* bm0b    = (const float*)d_in[13];
  const float* W_gcn1  = (const float*)d_in[14];
  const float* b_gcn1  = (const float*)d_in[15];
  const float* Wm1a    = (const float*)d_in[16];
  const float* bm1a    = (const float*)d_in[17];
  const float* Wm1b    = (const float*)d_in[18];
  const float* bm1b    = (const float*)d_in[19];
  const float* F0w     = (const float*)d_in[20];
  const float* F1w     = (const float*)d_in[21];
  const float* F2w     = (const float*)d_in[22];
  const float* Kc      = (const float*)d_in[23];
  const float* bc      = (const float*)d_in[24];
  const float* G0w     = (const float*)d_in[25];
  const float* G1w     = (const float*)d_in[26];
  const float* G2w     = (const float*)d_in[27];
  const float* H0w     = (const float*)d_in[28];
  const float* H1w     = (const float*)d_in[29];
  const float* H2w     = (const float*)d_in[30];
  const float* Wo1     = (const float*)d_in[31];
  const float* bo1     = (const float*)d_in[32];
  const float* Wo2     = (const float*)d_in[33];
  const float* bo2     = (const float*)d_in[34];
  float* ws  = (float*)d_ws;
  float* out = (float*)d_out;

  k0_setup<<<5, 256, 0, stream>>>(F0w, F2w, G0w, G2w, H0w, H2w, Wm0b, bm0b, W_gcn1, ws);
  kcsr<<<G_, 1024, 0, stream>>>(ei1, ei2, ws);
  k2_pool<<<G_, 1024, 0, stream>>>(x1, x2, W_score, b_score, ws);
  k3_graph<<<G_, 1024, 0, stream>>>(x1, x2, W_gcn0, b_gcn0, Wm0a, bm0a,
                                    b_gcn1, Wm1a, bm1a, ws);
  k4_pi<<<G_, 256, 0, stream>>>(PI1, PI2, Kc, bc, ws);
  k5_final<<<G_, 256, 0, stream>>>(Wm0b, bm0b, Wm1b, bm1b, F1w, G1w, H1w,
                                   Wo1, bo1, Wo2, bo2, ws, out);
}

// Round 3
// 297.089 us; speedup vs baseline: 4.6128x; 1.0256x over previous
//
#include <hip/hip_runtime.h>
#include <cstdint>

// ---------------------------------------------------------------------------
// TenGCN fused forward, atomic-free, spill-free.
// 128 graphs (2 branches x 64 batches). Scatter-adds are gathers over a
// per-graph dst-sorted CSR (kcsr); k2 compacts valid edges in-place after
// pooling so k3's convs run unchecked gathers. No float atomics anywhere.
// h1/h2 eliminated via W01 = Wm0b @ W_gcn1; tcl chain folded (k0).
// ---------------------------------------------------------------------------

constexpr int B_ = 64, N_ = 1024, E_ = 32768, F_ = 128, H_ = 32;
constexpr int CF_ = 5, P_ = 50, K_ = 512, G_ = 128, PO = 25;

// workspace offsets (in 4-byte units)
constexpr size_t WS_OFF   = 0;                                // G*1025 ints
constexpr size_t WS_SRCS  = WS_OFF + (size_t)G_*1025;         // G*E u16 (raw, then compacted)
constexpr size_t WS_ONODE = WS_SRCS + (size_t)G_*(E_/2);      // G*512 ints
constexpr size_t WS_VDEG  = WS_ONODE + (size_t)G_*K_;         // G*512 u16 -> G*256 u32
constexpr size_t WS_MR0   = WS_VDEG + (size_t)G_*(K_/2);      // G*32
constexpr size_t WS_MR1   = WS_MR0 + (size_t)G_*H_;           // G*32
constexpr size_t WS_PPI   = WS_MR1 + (size_t)G_*H_;           // G*25
constexpr size_t WS_H0M   = WS_PPI + (size_t)G_*PO;           // 64
constexpr size_t WS_H2M   = WS_H0M + 64;                      // 32
constexpr size_t WS_F0V   = WS_H2M + 32;                      // 2
constexpr size_t WS_F2V   = WS_F0V + 2;                       // 32
constexpr size_t WS_G0V   = WS_F2V + 32;                      // 32
constexpr size_t WS_G2V   = WS_G0V + 32;                      // 25 (pad 32)
constexpr size_t WS_B01   = WS_G2V + 32;                      // 32
constexpr size_t WS_W01   = WS_B01 + 32;                      // 1024

// swizzled column group: logical col j of row r lives at
// r*32 + (((j>>2) ^ ((r>>2)&7))<<2) + (j&3)
static __device__ __forceinline__ int swzf4(int row, int c4) {
  return row*32 + (((c4) ^ ((row >> 2) & 7)) << 2);
}

// ---------------------------------------------------------------------------
// kcsr: per-graph counting sort of edges by dst. int atomics only.
// ---------------------------------------------------------------------------
__global__ __launch_bounds__(1024, 4) void kcsr(
    const int* __restrict__ ei1, const int* __restrict__ ei2,
    float* __restrict__ ws)
{
  int g = blockIdx.x, br = g >> 6, b = g & 63;
  const int* ei  = (br ? ei2 : ei1) + (size_t)b*2*E_;
  const int* src = ei;
  const int* dst = ei + E_;
  int* offg = (int*)ws + WS_OFF + (size_t)g*1025;
  uint16_t* srcSg = (uint16_t*)(ws + WS_SRCS) + (size_t)g*E_;

  __shared__ uint16_t dstL[E_];   // 64KB
  __shared__ uint16_t srcL[E_];   // 64KB
  __shared__ int cnt[N_], fill[N_], offL[N_], sa[N_], sb[N_];

  int t = threadIdx.x;
  cnt[t] = 0; fill[t] = 0;
  __syncthreads();
  for (int e = t; e < E_; e += 1024) {
    int d = dst[e];
    dstL[e] = (uint16_t)d;
    atomicAdd(&cnt[d], 1);
  }
  __syncthreads();
  // Hillis-Steele inclusive scan over 1024 counts
  sa[t] = cnt[t];
  __syncthreads();
  int* cur = sa; int* nxt = sb;
  for (int s = 1; s < N_; s <<= 1) {
    int v = cur[t] + (t >= s ? cur[t - s] : 0);
    nxt[t] = v;
    __syncthreads();
    int* tmp = cur; cur = nxt; nxt = tmp;
  }
  int excl = cur[t] - cnt[t];
  offL[t] = excl;
  offg[t] = excl;
  if (t == 0) offg[N_] = E_;
  __syncthreads();
  for (int e = t; e < E_; e += 1024) {
    int d = dstL[e];
    int pos = offL[d] + atomicAdd(&fill[d], 1);
    srcL[pos] = (uint16_t)src[e];
  }
  __syncthreads();
  { const uint4* si = (const uint4*)srcL;
    uint4* so = (uint4*)srcSg;
    for (int i = t; i < E_*2/16; i += 1024) so[i] = si[i]; }
}

// ---------------------------------------------------------------------------
// k0: tiny precomputations.
// ---------------------------------------------------------------------------
__global__ __launch_bounds__(256) void k0_setup(
    const float* __restrict__ F0w, const float* __restrict__ F2w,
    const float* __restrict__ G0w, const float* __restrict__ G2w,
    const float* __restrict__ H0w, const float* __restrict__ H2w,
    const float* __restrict__ Wm0b, const float* __restrict__ bm0b,
    const float* __restrict__ Wg1, float* __restrict__ ws)
{
  int t = threadIdx.x;
  if (blockIdx.x == 0) {
    __shared__ float h0m[64], h2m[32];
    if (t < 64) { float s = 0.f; for (int p = 0; p < 64; ++p) s += H0w[p*64+t]; h0m[t] = s*(1.f/64.f); }
    if (t < 32) { float s = 0.f; for (int r = 0; r < 32; ++r) s += H2w[r*32+t]; h2m[t] = s*(1.f/32.f); }
    __syncthreads();
    if (t < 64) ws[WS_H0M+t] = h0m[t];
    if (t < 32) ws[WS_H2M+t] = h2m[t];
    if (t < 2)  { float s=0.f; for (int p=0;p<32;++p) s += F0w[p*2+t]*h0m[p];     ws[WS_F0V+t]=s; }
    if (t < 32) { float s=0.f; for (int r=0;r<32;++r) s += F2w[r*32+t]*h2m[r];    ws[WS_F2V+t]=s; }
    if (t < 32) { float s=0.f; for (int p=0;p<32;++p) s += G0w[p*32+t]*h0m[32+p]; ws[WS_G0V+t]=s; }
    if (t < PO) { float s=0.f; for (int r=0;r<32;++r) s += G2w[r*25+t]*h2m[r];    ws[WS_G2V+t]=s; }
    if (t < 32) { float s=0.f; for (int k=0;k<1024;++k) s += bm0b[k]*Wg1[k*32+t]; ws[WS_B01+t]=s; }
  } else {
    int o = (blockIdx.x-1)*256 + t;       // 0..1023
    int kk = o >> 5, j = o & 31;
    float s = 0.f;
    for (int tt = 0; tt < 1024; ++tt) s += Wm0b[kk*1024+tt]*Wg1[tt*32+j];
    ws[WS_W01+o] = s;
  }
}

// ---------------------------------------------------------------------------
// k2: score features (x@W_score), scoring GCN via CSR gather, top-512,
// then valid-edge compaction (in-place on srcS) + onode/vdeg emission.
// ---------------------------------------------------------------------------
__global__ __launch_bounds__(1024, 4) void k2_pool(
    const float* __restrict__ x1, const float* __restrict__ x2,
    const float* __restrict__ Wsc, const float* __restrict__ bsc,
    float* __restrict__ ws)
{
  int g = blockIdx.x, br = g >> 6, b = g & 63;
  const float* xg = (br ? x2 : x1) + (size_t)b*N_*F_;
  const int* offg = (const int*)ws + WS_OFF + (size_t)g*1025;
  uint16_t* srcS = (uint16_t*)(ws + WS_SRCS) + (size_t)g*E_;
  int* onodeg = (int*)ws + WS_ONODE + (size_t)g*K_;
  uint16_t* vdegg = (uint16_t*)(ws + WS_VDEG) + (size_t)g*K_;

  __shared__ float Ws[F_*10];       // 5KB
  __shared__ float hsd[N_*13];      // 52KB (odd row pitch: bank-uniform gathers)
  __shared__ float keyL[N_];
  __shared__ int   idxL[N_];
  __shared__ int   nidxL[N_];

  int t = threadIdx.x;
  for (int i = t; i < F_*10; i += 1024) Ws[i] = Wsc[i];
  int off0 = offg[t], off1 = offg[t+1];
  float dv = rsqrtf((float)(off1 - off0) + 1.0f);
  __syncthreads();

  // hs row for node t: x[t] @ W_score, pre-scaled by dinv[t]
  {
    const float4* xr = (const float4*)(xg + (size_t)t*F_);
    float acc[10] = {};
    for (int k4 = 0; k4 < 32; ++k4) {
      float4 v = xr[k4];
      const float* w = &Ws[k4*40];
      #pragma unroll
      for (int j = 0; j < 10; ++j)
        acc[j] += v.x*w[j] + v.y*w[10+j] + v.z*w[20+j] + v.w*w[30+j];
    }
    #pragma unroll
    for (int j = 0; j < 10; ++j) hsd[t*13+j] = acc[j]*dv;
  }
  __syncthreads();

  // gather over in-edges of node t (scalar reads, odd pitch -> no conflicts)
  {
    float agg[10] = {};
    for (int e = off0; e < off1; ++e) {
      int s = srcS[e];
      const float* hr = &hsd[s*13];
      #pragma unroll
      for (int j = 0; j < 10; ++j) agg[j] += hr[j];
    }
    float sc = 0.f;
    #pragma unroll
    for (int j = 0; j < 5; ++j) {
      float e0 = dv*(agg[2*j]   + hsd[t*13+2*j])   + bsc[2*j];
      float e1 = dv*(agg[2*j+1] + hsd[t*13+2*j+1]) + bsc[2*j+1];
      sc += fabsf(e1 - e0);
    }
    keyL[t] = sc; idxL[t] = t;
  }
  __syncthreads();

  // bitonic sort: (score desc, idx asc)
  for (int k = 2; k <= N_; k <<= 1) {
    for (int j = k >> 1; j > 0; j >>= 1) {
      int ixj = t ^ j;
      if (ixj > t) {
        float ka = keyL[t], kb = keyL[ixj];
        int   ia = idxL[t], ib = idxL[ixj];
        bool aAfter = (ka < kb) || (ka == kb && ia > ib);
        bool doSwap = ((t & k) == 0) ? aAfter : !aAfter;
        if (doSwap) { keyL[t]=kb; keyL[ixj]=ka; idxL[t]=ib; idxL[ixj]=ia; }
      }
      __syncthreads();
    }
  }
  nidxL[t] = -1;
  __syncthreads();
  if (t < K_) { nidxL[idxL[t]] = t; onodeg[t] = idxL[t]; }
  __syncthreads();

  // compaction: thread t owns node t's CSR segment; rewrite valid edges
  // in-place as new-index u16, emit valid count.
  {
    int ii = nidxL[t];
    if (ii >= 0) {
      int c = 0;
      for (int e = off0; e < off1; ++e) {
        int m = nidxL[srcS[e]];
        if (m >= 0) { srcS[off0 + c] = (uint16_t)m; ++c; }
      }
      vdegg[ii] = (uint16_t)c;
    }
  }
}

// ---------------------------------------------------------------------------
// 512x32 @ 32x32 matmul on swizzled LDS buffers. W padded [32][36].
// ---------------------------------------------------------------------------
static __device__ __forceinline__ void mm32(
    const float* __restrict__ S, float* __restrict__ D,
    const float* __restrict__ Wp, const float* __restrict__ bias,
    const float* __restrict__ rowscale, bool do_relu, int t)
{
  const int it = t >> 3, jt = t & 7;
  const int i0 = it*4;
  const int swa = it & 7;
  float acc[4][4] = {};
  #pragma unroll
  for (int kv = 0; kv < 8; ++kv) {
    float4 w0 = *(const float4*)&Wp[(kv*4+0)*36 + jt*4];
    float4 w1 = *(const float4*)&Wp[(kv*4+1)*36 + jt*4];
    float4 w2 = *(const float4*)&Wp[(kv*4+2)*36 + jt*4];
    float4 w3 = *(const float4*)&Wp[(kv*4+3)*36 + jt*4];
    #pragma unroll
    for (int d = 0; d < 4; ++d) {
      float4 a = *(const float4*)&S[(i0+d)*32 + ((kv ^ swa) << 2)];
      acc[d][0] += a.x*w0.x + a.y*w1.x + a.z*w2.x + a.w*w3.x;
      acc[d][1] += a.x*w0.y + a.y*w1.y + a.z*w2.y + a.w*w3.y;
      acc[d][2] += a.x*w0.z + a.y*w1.z + a.z*w2.z + a.w*w3.z;
      acc[d][3] += a.x*w0.w + a.y*w1.w + a.z*w2.w + a.w*w3.w;
    }
  }
  float b0 = bias[jt*4+0], b1 = bias[jt*4+1], b2 = bias[jt*4+2], b3 = bias[jt*4+3];
  #pragma unroll
  for (int d = 0; d < 4; ++d) {
    int row = i0 + d;
    float v0 = acc[d][0]+b0, v1 = acc[d][1]+b1, v2 = acc[d][2]+b2, v3 = acc[d][3]+b3;
    if (do_relu) { v0=fmaxf(v0,0.f); v1=fmaxf(v1,0.f); v2=fmaxf(v2,0.f); v3=fmaxf(v3,0.f); }
    if (rowscale) { float rs = rowscale[row]; v0*=rs; v1*=rs; v2*=rs; v3*=rs; }
    float4 o; o.x=v0; o.y=v1; o.z=v2; o.w=v3;
    *(float4*)&D[row*32 + ((jt ^ swa) << 2)] = o;
  }
}

// ---------------------------------------------------------------------------
// gather conv over compacted valid edges:
// D[dd] = dinv[dd]*(sum_valid S[ss] + S[dd]) + bias.  thread=(dd, half).
// ---------------------------------------------------------------------------
static __device__ __forceinline__ void gatherconv(
    const float* __restrict__ S, float* __restrict__ D,
    const float* __restrict__ bias,
    const float* __restrict__ dinv, const int* __restrict__ eoff,
    const int* __restrict__ vcnt, const uint16_t* __restrict__ srcS, int t)
{
  int dd = t & 511, half = t >> 9;
  int lo = eoff[dd], n = vcnt[dd];
  int c0g = half*4;     // logical col groups c0g..c0g+3
  float4 a0 = {0,0,0,0}, a1 = a0, a2 = a0, a3 = a0;
  for (int i = 0; i < n; ++i) {
    int ss = srcS[lo + i];
    float4 v;
    v = *(const float4*)&S[swzf4(ss, c0g+0)]; a0.x+=v.x; a0.y+=v.y; a0.z+=v.z; a0.w+=v.w;
    v = *(const float4*)&S[swzf4(ss, c0g+1)]; a1.x+=v.x; a1.y+=v.y; a1.z+=v.z; a1.w+=v.w;
    v = *(const float4*)&S[swzf4(ss, c0g+2)]; a2.x+=v.x; a2.y+=v.y; a2.z+=v.z; a2.w+=v.w;
    v = *(const float4*)&S[swzf4(ss, c0g+3)]; a3.x+=v.x; a3.y+=v.y; a3.z+=v.z; a3.w+=v.w;
  }
  float dvd = dinv[dd];
  float4 s0 = *(const float4*)&S[swzf4(dd, c0g+0)];
  float4 s1 = *(const float4*)&S[swzf4(dd, c0g+1)];
  float4 s2 = *(const float4*)&S[swzf4(dd, c0g+2)];
  float4 s3 = *(const float4*)&S[swzf4(dd, c0g+3)];
  int cb = half*16;
  float4 r0, r1, r2, r3;
  r0.x = dvd*(a0.x+s0.x) + bias[cb+0];  r0.y = dvd*(a0.y+s0.y) + bias[cb+1];
  r0.z = dvd*(a0.z+s0.z) + bias[cb+2];  r0.w = dvd*(a0.w+s0.w) + bias[cb+3];
  r1.x = dvd*(a1.x+s1.x) + bias[cb+4];  r1.y = dvd*(a1.y+s1.y) + bias[cb+5];
  r1.z = dvd*(a1.z+s1.z) + bias[cb+6];  r1.w = dvd*(a1.w+s1.w) + bias[cb+7];
  r2.x = dvd*(a2.x+s2.x) + bias[cb+8];  r2.y = dvd*(a2.y+s2.y) + bias[cb+9];
  r2.z = dvd*(a2.z+s2.z) + bias[cb+10]; r2.w = dvd*(a2.w+s2.w) + bias[cb+11];
  r3.x = dvd*(a3.x+s3.x) + bias[cb+12]; r3.y = dvd*(a3.y+s3.y) + bias[cb+13];
  r3.z = dvd*(a3.z+s3.z) + bias[cb+14]; r3.w = dvd*(a3.w+s3.w) + bias[cb+15];
  *(float4*)&D[swzf4(dd, c0g+0)] = r0;
  *(float4*)&D[swzf4(dd, c0g+1)] = r1;
  *(float4*)&D[swzf4(dd, c0g+2)] = r2;
  *(float4*)&D[swzf4(dd, c0g+3)] = r3;
}

// ---------------------------------------------------------------------------
// k3: pooled per-graph pipeline, atomic-free, spill-free.
// ---------------------------------------------------------------------------
__global__ __launch_bounds__(1024, 4) void k3_graph(
    const float* __restrict__ x1, const float* __restrict__ x2,
    const float* __restrict__ Wg0, const float* __restrict__ bg0,
    const float* __restrict__ Wm0a, const float* __restrict__ bm0a,
    const float* __restrict__ bg1, const float* __restrict__ Wm1a,
    const float* __restrict__ bm1a, float* __restrict__ ws)
{
  int g = blockIdx.x, br = g >> 6, b = g & 63;
  const float* xg = (br ? x2 : x1) + (size_t)b*N_*F_;
  const int* offg  = (const int*)ws + WS_OFF + (size_t)g*1025;
  const int* onodeg = (const int*)ws + WS_ONODE + (size_t)g*K_;
  const uint16_t* vdegg = (const uint16_t*)(ws + WS_VDEG) + (size_t)g*K_;
  const uint16_t* srcS = (const uint16_t*)(ws + WS_SRCS) + (size_t)g*E_;

  __shared__ float bufA[K_*H_];   // 64KB
  __shared__ float bufB[K_*H_];   // 64KB
  __shared__ float wbuf[F_*36];   // 18KB
  __shared__ float dinv[K_];      // 2KB
  __shared__ int   onode[K_];     // 2KB
  __shared__ int   eoff[K_];      // 2KB
  __shared__ int   vcnt[K_];      // 2KB

  const int t = threadIdx.x;

  // P0: loads
  if (t < K_) {
    int o = onodeg[t];
    onode[t] = o;
    eoff[t] = offg[o];
    int vc = vdegg[t];
    vcnt[t] = vc;
    dinv[t] = rsqrtf((float)vc + 1.0f);
  }
  for (int i = t; i < F_*H_; i += 1024) wbuf[(i >> 5)*36 + (i & 31)] = Wg0[i];
  __syncthreads();

  // P2: bufA = rowscale(X[onode] @ Wg0)
  {
    const int it = t >> 3, jt = t & 7;
    const int i0 = it*4;
    const float* xr0 = xg + (size_t)onode[i0+0]*F_;
    const float* xr1 = xg + (size_t)onode[i0+1]*F_;
    const float* xr2 = xg + (size_t)onode[i0+2]*F_;
    const float* xr3 = xg + (size_t)onode[i0+3]*F_;
    float acc[4][4] = {};
    for (int k4 = 0; k4 < 32; ++k4) {
      float4 w0 = *(const float4*)&wbuf[(k4*4+0)*36 + jt*4];
      float4 w1 = *(const float4*)&wbuf[(k4*4+1)*36 + jt*4];
      float4 w2 = *(const float4*)&wbuf[(k4*4+2)*36 + jt*4];
      float4 w3 = *(const float4*)&wbuf[(k4*4+3)*36 + jt*4];
      float4 a;
      a = *(const float4*)(xr0 + k4*4);
      acc[0][0]+=a.x*w0.x+a.y*w1.x+a.z*w2.x+a.w*w3.x; acc[0][1]+=a.x*w0.y+a.y*w1.y+a.z*w2.y+a.w*w3.y;
      acc[0][2]+=a.x*w0.z+a.y*w1.z+a.z*w2.z+a.w*w3.z; acc[0][3]+=a.x*w0.w+a.y*w1.w+a.z*w2.w+a.w*w3.w;
      a = *(const float4*)(xr1 + k4*4);
      acc[1][0]+=a.x*w0.x+a.y*w1.x+a.z*w2.x+a.w*w3.x; acc[1][1]+=a.x*w0.y+a.y*w1.y+a.z*w2.y+a.w*w3.y;
      acc[1][2]+=a.x*w0.z+a.y*w1.z+a.z*w2.z+a.w*w3.z; acc[1][3]+=a.x*w0.w+a.y*w1.w+a.z*w2.w+a.w*w3.w;
      a = *(const float4*)(xr2 + k4*4);
      acc[2][0]+=a.x*w0.x+a.y*w1.x+a.z*w2.x+a.w*w3.x; acc[2][1]+=a.x*w0.y+a.y*w1.y+a.z*w2.y+a.w*w3.y;
      acc[2][2]+=a.x*w0.z+a.y*w1.z+a.z*w2.z+a.w*w3.z; acc[2][3]+=a.x*w0.w+a.y*w1.w+a.z*w2.w+a.w*w3.w;
      a = *(const float4*)(xr3 + k4*4);
      acc[3][0]+=a.x*w0.x+a.y*w1.x+a.z*w2.x+a.w*w3.x; acc[3][1]+=a.x*w0.y+a.y*w1.y+a.z*w2.y+a.w*w3.y;
      acc[3][2]+=a.x*w0.z+a.y*w1.z+a.z*w2.z+a.w*w3.z; acc[3][3]+=a.x*w0.w+a.y*w1.w+a.z*w2.w+a.w*w3.w;
    }
    #pragma unroll
    for (int d = 0; d < 4; ++d) {
      int row = i0 + d;
      float rs = dinv[row];
      float4 o; o.x=acc[d][0]*rs; o.y=acc[d][1]*rs; o.z=acc[d][2]*rs; o.w=acc[d][3]*rs;
      *(float4*)&bufA[row*32 + ((jt ^ (it & 7)) << 2)] = o;
    }
  }
  __syncthreads();

  // P3: small weights into wbuf (Wm0a | W01 | Wm1a), [32][36] each
  { int k = t >> 5, j = t & 31;
    wbuf[0    + k*36 + j] = Wm0a[t];
    wbuf[1152 + k*36 + j] = ws[WS_W01 + t];
    wbuf[2304 + k*36 + j] = Wm1a[t]; }
  __syncthreads();

  // P4: conv0 gather: bufB = c0
  gatherconv(bufA, bufB, bg0, dinv, eoff, vcnt, srcS, t);
  __syncthreads();

  // P6: r0 = relu(c0 @ Wm0a + bm0a) -> bufA
  mm32(bufB, bufA, &wbuf[0], bm0a, nullptr, true, t);
  __syncthreads();

  // P7: meanr0 (scratch = bufB[0..1023])
  { int j = t & 31, grp = t >> 5;
    float s = 0.f;
    for (int i = grp*16; i < grp*16 + 16; ++i)
      s += bufA[i*32 + ((((j >> 2) ^ ((i >> 2) & 7)) << 2) | (j & 3))];
    bufB[t] = s; }
  __syncthreads();
  if (t < 32) {
    float s = 0.f;
    #pragma unroll
    for (int q = 0; q < 32; ++q) s += bufB[q*32 + t];
    ws[WS_MR0 + (size_t)g*H_ + t] = s * (1.0f/512.0f);
  }
  __syncthreads();

  // P8: hnew2 = (r0 @ W01 + b01) * dinv -> bufB
  mm32(bufA, bufB, &wbuf[1152], ws + WS_B01, dinv, false, t);
  __syncthreads();

  // P9: conv1 gather: bufA = c1
  gatherconv(bufB, bufA, bg1, dinv, eoff, vcnt, srcS, t);
  __syncthreads();

  // P11: r1 = relu(c1 @ Wm1a + bm1a) -> bufB
  mm32(bufA, bufB, &wbuf[2304], bm1a, nullptr, true, t);
  __syncthreads();

  // P12: meanr1 (scratch = bufA[0..1023])
  { int j = t & 31, grp = t >> 5;
    float s = 0.f;
    for (int i = grp*16; i < grp*16 + 16; ++i)
      s += bufB[i*32 + ((((j >> 2) ^ ((i >> 2) & 7)) << 2) | (j & 3))];
    bufA[t] = s; }
  __syncthreads();
  if (t < 32) {
    float s = 0.f;
    #pragma unroll
    for (int q = 0; q < 32; ++q) s += bufA[q*32 + t];
    ws[WS_MR1 + (size_t)g*H_ + t] = s * (1.0f/512.0f);
  }
}

// ---------------------------------------------------------------------------
// k4: PI conv + relu, reduced by g0v/g2v. thread=(jp,sub) + shfl.
// ---------------------------------------------------------------------------
__global__ __launch_bounds__(256) void k4_pi(
    const float* __restrict__ PI1, const float* __restrict__ PI2,
    const float* __restrict__ Kc, const float* __restrict__ bc,
    float* __restrict__ ws)
{
  int g = blockIdx.x, br = g >> 6, b = g & 63;
  const float* pig = (br ? PI2 : PI1) + (size_t)b*CF_*P_*P_;
  __shared__ float PIt[CF_*P_*P_];   // 50KB
  __shared__ float KcL[H_*CF_*4];
  __shared__ float bcL[H_], g0L[H_], g2L[PO];
  int t = threadIdx.x;
  for (int i = t; i < CF_*P_*P_; i += 256) PIt[i] = pig[i];
  for (int i = t; i < H_*CF_*4; i += 256) KcL[i] = Kc[i];
  if (t < 32) { bcL[t] = bc[t]; g0L[t] = ws[WS_G0V + t]; }
  if (t >= 32 && t < 32+PO) g2L[t-32] = ws[WS_G2V + (t-32)];
  __syncthreads();
  int jp = t >> 3, sub = t & 7;
  float acc = 0.f;
  if (jp < PO) {
    for (int i = sub; i < H_; i += 8) {
      const float* kcp = &KcL[i*20];
      float bi = bcL[i], gi = g0L[i];
      for (int kp = 0; kp < PO; ++kp) {
        float v = bi;
        #pragma unroll
        for (int c = 0; c < CF_; ++c) {
          const float* pp = &PIt[c*2500 + (2*jp)*50 + 2*kp];
          v += pp[0]*kcp[c*4+0] + pp[1]*kcp[c*4+1] + pp[50]*kcp[c*4+2] + pp[51]*kcp[c*4+3];
        }
        acc += fmaxf(v, 0.f) * gi * g2L[kp];
      }
    }
  }
  #pragma unroll
  for (int d = 4; d > 0; d >>= 1) acc += __shfl_down(acc, d, 8);
  if (sub == 0 && jp < PO) ws[WS_PPI + (size_t)g*PO + jp] = acc;
}

// ---------------------------------------------------------------------------
// k5: per-graph tail.
// ---------------------------------------------------------------------------
__global__ __launch_bounds__(256) void k5_final(
    const float* __restrict__ Wm0b, const float* __restrict__ bm0b,
    const float* __restrict__ Wm1b, const float* __restrict__ bm1b,
    const float* __restrict__ F1w, const float* __restrict__ G1w,
    const float* __restrict__ H1w, const float* __restrict__ Wo1,
    const float* __restrict__ bo1, const float* __restrict__ Wo2,
    const float* __restrict__ bo2, const float* __restrict__ ws,
    float* __restrict__ out)
{
  int g = blockIdx.x, t = threadIdx.x;
  __shared__ float m1L[1024], m2L[1024];
  __shared__ float mr0[32], mr1[32], AL[32], TL[32], pl[32], zl[32], ppi[PO];
  if (t < 32) { mr0[t] = ws[WS_MR0 + (size_t)g*H_ + t]; mr1[t] = ws[WS_MR1 + (size_t)g*H_ + t]; }
  if (t >= 32 && t < 32+PO) ppi[t-32] = ws[WS_PPI + (size_t)g*PO + (t-32)];
  __syncthreads();
  #pragma unroll
  for (int s = 0; s < 4; ++s) {
    int cc = t + s*256;
    float a1 = bm0b[cc], a2 = bm1b[cc];
    for (int k = 0; k < 32; ++k) {
      a1 += mr0[k]*Wm0b[k*1024 + cc];
      a2 += mr1[k]*Wm1b[k*1024 + cc];
    }
    m1L[cc] = a1; m2L[cc] = a2;
  }
  __syncthreads();
  float f00 = ws[WS_F0V], f01 = ws[WS_F0V+1];
  if (t < 32) {
    float s = 0.f;
    for (int kp = 0; kp < 32; ++kp)
      s += ws[WS_F2V + kp] * (f00*m1L[t*32+kp] + f01*m2L[t*32+kp]);
    AL[t] = s;
  }
  __syncthreads();
  if (t < 32) {
    float s = 0.f;
    for (int jp = 0; jp < 32; ++jp) s += F1w[t*32+jp]*AL[jp];
    for (int jp = 0; jp < PO; ++jp) s += G1w[t*25+jp]*ppi[jp];
    TL[t] = s;
  }
  __syncthreads();
  if (t < 32) {
    float s = 0.f;
    for (int j = 0; j < 32; ++j) s += H1w[t*32+j]*TL[j];
    pl[t] = s;
  }
  __syncthreads();
  if (t < 32) {
    float s = bo1[t];
    for (int j = 0; j < 32; ++j) s += pl[j]*Wo1[j*32+t];
    zl[t] = fmaxf(s, 0.f);
  }
  __syncthreads();
  if (t < 2) {
    float s = bo2[t];
    for (int q = 0; q < 32; ++q) s += zl[q]*Wo2[q*2+t];
    int br = g >> 6, b = g & 63;
    out[br*(B_*2) + b*2 + t] = s;
  }
}

// ---------------------------------------------------------------------------
extern "C" void kernel_launch(void* const* d_in, const int* in_sizes, int n_in,
                              void* d_out, int out_size, void* d_ws, size_t ws_size,
                              hipStream_t stream) {
  (void)in_sizes; (void)n_in; (void)out_size; (void)ws_size;
  const float* x1      = (const float*)d_in[0];
  const int*   ei1     = (const int*)  d_in[1];
  const float* PI1     = (const float*)d_in[2];
  const float* x2      = (const float*)d_in[3];
  const int*   ei2     = (const int*)  d_in[4];
  const float* PI2     = (const float*)d_in[5];
  const float* W_score = (const float*)d_in[6];
  const float* b_score = (const float*)d_in[7];
  const float* W_gcn0  = (const float*)d_in[8];
  const float* b_gcn0  = (const float*)d_in[9];
  const float* Wm0a    = (const float*)d_in[10];
  const float* bm0a    = (const float*)d_in[11];
  const float* Wm0b    = (const float*)d_in[12];
  const float* bm0b    = (const float*)d_in[13];
  const float* W_gcn1  = (const float*)d_in[14];
  const float* b_gcn1  = (const float*)d_in[15];
  const float* Wm1a    = (const float*)d_in[16];
  const float* bm1a    = (const float*)d_in[17];
  const float* Wm1b    = (const float*)d_in[18];
  const float* bm1b    = (const float*)d_in[19];
  const float* F0w     = (const float*)d_in[20];
  const float* F1w     = (const float*)d_in[21];
  const float* F2w     = (const float*)d_in[22];
  const float* Kc      = (const float*)d_in[23];
  const float* bc      = (const float*)d_in[24];
  const float* G0w     = (const float*)d_in[25];
  const float* G1w     = (const float*)d_in[26];
  const float* G2w     = (const float*)d_in[27];
  const float* H0w     = (const float*)d_in[28];
  const float* H1w     = (const float*)d_in[29];
  const float* H2w     = (const float*)d_in[30];
  const float* Wo1     = (const float*)d_in[31];
  const float* bo1     = (const float*)d_in[32];
  const float* Wo2     = (const float*)d_in[33];
  const float* bo2     = (const float*)d_in[34];
  float* ws  = (float*)d_ws;
  float* out = (float*)d_out;

  k0_setup<<<5, 256, 0, stream>>>(F0w, F2w, G0w, G2w, H0w, H2w, Wm0b, bm0b, W_gcn1, ws);
  kcsr<<<G_, 1024, 0, stream>>>(ei1, ei2, ws);
  k2_pool<<<G_, 1024, 0, stream>>>(x1, x2, W_score, b_score, ws);
  k3_graph<<<G_, 1024, 0, stream>>>(x1, x2, W_gcn0, b_gcn0, Wm0a, bm0a,
                                    b_gcn1, Wm1a, bm1a, ws);
  k4_pi<<<G_, 256, 0, stream>>>(PI1, PI2, Kc, bc, ws);
  k5_final<<<G_, 256, 0, stream>>>(Wm0b, bm0b, Wm1b, bm1b, F1w, G1w, H1w,
                                   Wo1, bo1, Wo2, bo2, ws, out);
}

// Round 4
// 236.012 us; speedup vs baseline: 5.8066x; 1.2588x over previous
//
#include <hip/hip_runtime.h>
#include <cstdint>

// ---------------------------------------------------------------------------
// TenGCN fused forward. 128 graphs (2 branches x 64 batches).
// Atomic-free (gathers over dst-sorted CSR). Graph pipeline split into
// small-LDS kernels at 256 WGs for full-chip occupancy. Wm0b/Wm1b folded
// into 32x32 matrices in k0 (P0b/P1b). h1/h2 eliminated via W01.
// ---------------------------------------------------------------------------

constexpr int B_ = 64, N_ = 1024, E_ = 32768, F_ = 128, H_ = 32;
constexpr int CF_ = 5, P_ = 50, K_ = 512, G_ = 128, PO = 25;

// workspace offsets (4-byte units)
constexpr size_t WS_OFF   = 0;                                // G*1025 int
constexpr size_t WS_SRCS  = WS_OFF + (size_t)G_*1025;         // G*E u16
constexpr size_t WS_ONODE = WS_SRCS + (size_t)G_*(E_/2);      // G*512 int
constexpr size_t WS_VDEG  = WS_ONODE + (size_t)G_*K_;         // G*512 u16
constexpr size_t WS_EOFF  = WS_VDEG + (size_t)G_*(K_/2);      // G*512 int
constexpr size_t WS_DINV  = WS_EOFF + (size_t)G_*K_;          // G*512 f32
constexpr size_t WS_GA    = WS_DINV + (size_t)G_*K_;          // G*512*32 f32
constexpr size_t WS_GC    = WS_GA + (size_t)G_*K_*H_;         // G*512*32 f32
constexpr size_t WS_PM0   = WS_GC + (size_t)G_*K_*H_;         // G*2*32
constexpr size_t WS_PM1   = WS_PM0 + (size_t)G_*64;           // G*2*32
constexpr size_t WS_PPI   = WS_PM1 + (size_t)G_*64;           // G*32
constexpr size_t WS_H0M   = WS_PPI + (size_t)G_*32;           // 64
constexpr size_t WS_H2M   = WS_H0M + 64;                      // 32
constexpr size_t WS_F0V   = WS_H2M + 32;                      // 2
constexpr size_t WS_F2V   = WS_F0V + 2;                       // 32
constexpr size_t WS_G0V   = WS_F2V + 32;                      // 32
constexpr size_t WS_G2V   = WS_G0V + 32;                      // 32 (25 used)
constexpr size_t WS_B01   = WS_G2V + 32;                      // 32
constexpr size_t WS_C0B   = WS_B01 + 32;                      // 32
constexpr size_t WS_C1B   = WS_C0B + 32;                      // 32
constexpr size_t WS_W01   = WS_C1B + 32;                      // 1024
constexpr size_t WS_P0B   = WS_W01 + 1024;                    // 1024
constexpr size_t WS_P1B   = WS_P0B + 1024;                    // 1024

// swizzled column group: logical group c4 (0..7) of row r lives at
// r*32 + ((c4 ^ ((r>>2)&7))<<2)
static __device__ __forceinline__ int swzf4(int row, int c4) {
  return row*32 + (((c4) ^ ((row >> 2) & 7)) << 2);
}

// ---------------------------------------------------------------------------
// kcsr: per-graph counting sort of edges by dst. int atomics only.
// ---------------------------------------------------------------------------
__global__ __launch_bounds__(1024, 4) void kcsr(
    const int* __restrict__ ei1, const int* __restrict__ ei2,
    float* __restrict__ ws)
{
  int g = blockIdx.x, br = g >> 6, b = g & 63;
  const int* ei  = (br ? ei2 : ei1) + (size_t)b*2*E_;
  const int* src = ei;
  const int* dst = ei + E_;
  int* offg = (int*)ws + WS_OFF + (size_t)g*1025;
  uint16_t* srcSg = (uint16_t*)(ws + WS_SRCS) + (size_t)g*E_;

  __shared__ uint16_t dstL[E_];   // 64KB
  __shared__ uint16_t srcL[E_];   // 64KB
  __shared__ int cnt[N_], fill[N_], offL[N_], sa[N_], sb[N_];

  int t = threadIdx.x;
  cnt[t] = 0; fill[t] = 0;
  __syncthreads();
  for (int e = t; e < E_; e += 1024) {
    int d = dst[e];
    dstL[e] = (uint16_t)d;
    atomicAdd(&cnt[d], 1);
  }
  __syncthreads();
  sa[t] = cnt[t];
  __syncthreads();
  int* cur = sa; int* nxt = sb;
  for (int s = 1; s < N_; s <<= 1) {
    int v = cur[t] + (t >= s ? cur[t - s] : 0);
    nxt[t] = v;
    __syncthreads();
    int* tmp = cur; cur = nxt; nxt = tmp;
  }
  int excl = cur[t] - cnt[t];
  offL[t] = excl;
  offg[t] = excl;
  if (t == 0) offg[N_] = E_;
  __syncthreads();
  for (int e = t; e < E_; e += 1024) {
    int d = dstL[e];
    int pos = offL[d] + atomicAdd(&fill[d], 1);
    srcL[pos] = (uint16_t)src[e];
  }
  __syncthreads();
  { const uint4* si = (const uint4*)srcL;
    uint4* so = (uint4*)srcSg;
    for (int i = t; i < E_*2/16; i += 1024) so[i] = si[i]; }
}

// ---------------------------------------------------------------------------
// k0: precomputations. block0: vectors; 1-4: W01; 5: P0b+c0b; 6: P1b+c1b.
// ---------------------------------------------------------------------------
__global__ __launch_bounds__(256) void k0_setup(
    const float* __restrict__ F0w, const float* __restrict__ F2w,
    const float* __restrict__ G0w, const float* __restrict__ G2w,
    const float* __restrict__ H0w, const float* __restrict__ H2w,
    const float* __restrict__ Wm0b, const float* __restrict__ bm0b,
    const float* __restrict__ Wm1b, const float* __restrict__ bm1b,
    const float* __restrict__ Wg1, float* __restrict__ ws)
{
  int t = threadIdx.x;
  int blk = blockIdx.x;
  if (blk == 0) {
    __shared__ float h0m[64], h2m[32];
    if (t < 64) { float s = 0.f; for (int p = 0; p < 64; ++p) s += H0w[p*64+t]; h0m[t] = s*(1.f/64.f); }
    if (t < 32) { float s = 0.f; for (int r = 0; r < 32; ++r) s += H2w[r*32+t]; h2m[t] = s*(1.f/32.f); }
    __syncthreads();
    if (t < 64) ws[WS_H0M+t] = h0m[t];
    if (t < 32) ws[WS_H2M+t] = h2m[t];
    if (t < 2)  { float s=0.f; for (int p=0;p<32;++p) s += F0w[p*2+t]*h0m[p];     ws[WS_F0V+t]=s; }
    if (t < 32) { float s=0.f; for (int r=0;r<32;++r) s += F2w[r*32+t]*h2m[r];    ws[WS_F2V+t]=s; }
    if (t < 32) { float s=0.f; for (int p=0;p<32;++p) s += G0w[p*32+t]*h0m[32+p]; ws[WS_G0V+t]=s; }
    if (t < PO) { float s=0.f; for (int r=0;r<32;++r) s += G2w[r*25+t]*h2m[r];    ws[WS_G2V+t]=s; }
    if (t < 32) { float s=0.f; for (int k=0;k<1024;++k) s += bm0b[k]*Wg1[k*32+t]; ws[WS_B01+t]=s; }
  } else if (blk <= 4) {
    int o = (blk-1)*256 + t;       // 0..1023
    int kk = o >> 5, j = o & 31;
    float s = 0.f;
    for (int tt = 0; tt < 1024; ++tt) s += Wm0b[kk*1024+tt]*Wg1[tt*32+j];
    ws[WS_W01+o] = s;
  } else {
    // P0b (blk 5) / P1b (blk 6): recompute f2v locally, then fold
    const float* Wb = (blk == 5) ? Wm0b : Wm1b;
    const float* bb = (blk == 5) ? bm0b : bm1b;
    size_t dstP = (blk == 5) ? WS_P0B : WS_P1B;
    size_t dstC = (blk == 5) ? WS_C0B : WS_C1B;
    __shared__ float h2mL[32], f2vL[32];
    if (t < 32) { float s = 0.f; for (int r = 0; r < 32; ++r) s += H2w[r*32+t]; h2mL[t] = s*(1.f/32.f); }
    __syncthreads();
    if (t < 32) { float s = 0.f; for (int r = 0; r < 32; ++r) s += F2w[r*32+t]*h2mL[r]; f2vL[t] = s; }
    __syncthreads();
    #pragma unroll
    for (int q = 0; q < 4; ++q) {
      int e = t*4 + q;            // 0..1023
      int k = e >> 5, c = e & 31;
      float s = 0.f;
      for (int kp = 0; kp < 32; ++kp) s += Wb[k*1024 + c*32 + kp]*f2vL[kp];
      ws[dstP + e] = s;
    }
    if (t < 32) { float s = 0.f; for (int kp = 0; kp < 32; ++kp) s += bb[t*32+kp]*f2vL[kp]; ws[dstC+t] = s; }
  }
}

// ---------------------------------------------------------------------------
// k2: 5 diff-features (x@Wdiff)*dinv, scoring gather, top-512 bitonic,
// valid-edge compaction + onode/vdeg/eoff/dinv emission.
// ---------------------------------------------------------------------------
__global__ __launch_bounds__(1024, 4) void k2_pool(
    const float* __restrict__ x1, const float* __restrict__ x2,
    const float* __restrict__ Wsc, const float* __restrict__ bsc,
    float* __restrict__ ws)
{
  int g = blockIdx.x, br = g >> 6, b = g & 63;
  const float* xg = (br ? x2 : x1) + (size_t)b*N_*F_;
  const int* offg = (const int*)ws + WS_OFF + (size_t)g*1025;
  uint16_t* srcS = (uint16_t*)(ws + WS_SRCS) + (size_t)g*E_;
  int* onodeg = (int*)ws + WS_ONODE + (size_t)g*K_;
  uint16_t* vdegg = (uint16_t*)(ws + WS_VDEG) + (size_t)g*K_;
  int* eoffg = (int*)ws + WS_EOFF + (size_t)g*K_;
  float* dinvg = ws + WS_DINV + (size_t)g*K_;

  __shared__ float WdL[F_*5];       // 2.5KB
  __shared__ float bdL[8];
  __shared__ float Dsc[N_*5];       // 20KB, odd pitch 5
  __shared__ float keyL[N_];
  __shared__ int   idxL[N_];
  __shared__ int   nidxL[N_];

  int t = threadIdx.x;
  if (t < F_) {
    #pragma unroll
    for (int j = 0; j < 5; ++j) WdL[t*5+j] = Wsc[t*10+2*j+1] - Wsc[t*10+2*j];
  }
  if (t < 5) bdL[t] = bsc[2*t+1] - bsc[2*t];
  int off0 = offg[t], off1 = offg[t+1];
  float dv = rsqrtf((float)(off1 - off0) + 1.0f);
  __syncthreads();

  // Dsc row for node t
  {
    const float4* xr = (const float4*)(xg + (size_t)t*F_);
    float acc[5] = {};
    for (int k4 = 0; k4 < 32; ++k4) {
      float4 v = xr[k4];
      const float* w = &WdL[k4*20];
      #pragma unroll
      for (int j = 0; j < 5; ++j)
        acc[j] += v.x*w[j] + v.y*w[5+j] + v.z*w[10+j] + v.w*w[15+j];
    }
    #pragma unroll
    for (int j = 0; j < 5; ++j) Dsc[t*5+j] = acc[j]*dv;
  }
  __syncthreads();

  // gather over in-edges of node t
  {
    float agg[5] = {};
    for (int e = off0; e < off1; ++e) {
      int s = srcS[e];
      const float* hr = &Dsc[s*5];
      #pragma unroll
      for (int j = 0; j < 5; ++j) agg[j] += hr[j];
    }
    float sc = 0.f;
    #pragma unroll
    for (int j = 0; j < 5; ++j)
      sc += fabsf(dv*(agg[j] + Dsc[t*5+j]) + bdL[j]);
    keyL[t] = sc; idxL[t] = t;
  }
  __syncthreads();

  // bitonic sort: (score desc, idx asc)
  for (int k = 2; k <= N_; k <<= 1) {
    for (int j = k >> 1; j > 0; j >>= 1) {
      int ixj = t ^ j;
      if (ixj > t) {
        float ka = keyL[t], kb = keyL[ixj];
        int   ia = idxL[t], ib = idxL[ixj];
        bool aAfter = (ka < kb) || (ka == kb && ia > ib);
        bool doSwap = ((t & k) == 0) ? aAfter : !aAfter;
        if (doSwap) { keyL[t]=kb; keyL[ixj]=ka; idxL[t]=ib; idxL[ixj]=ia; }
      }
      __syncthreads();
    }
  }
  nidxL[t] = -1;
  __syncthreads();
  if (t < K_) { nidxL[idxL[t]] = t; onodeg[t] = idxL[t]; }
  __syncthreads();

  // compaction: thread t owns node t's CSR segment
  {
    int ii = nidxL[t];
    if (ii >= 0) {
      int c = 0;
      for (int e = off0; e < off1; ++e) {
        int m = nidxL[srcS[e]];
        if (m >= 0) { srcS[off0 + c] = (uint16_t)m; ++c; }
      }
      vdegg[ii] = (uint16_t)c;
      eoffg[ii] = off0;
      dinvg[ii] = rsqrtf((float)c + 1.0f);
    }
  }
}

// ---------------------------------------------------------------------------
// 256x32 @ 32x32 matmul core: S swizzled LDS [256][32], Wp LDS [32][36].
// 512 threads: it=t>>3 (64 row-quads), jt=t&7 (col-quads). acc out in regs.
// ---------------------------------------------------------------------------
static __device__ __forceinline__ void mmA(
    const float* __restrict__ S, const float* __restrict__ Wp,
    float (&acc)[4][4], int it, int jt)
{
  const int i0 = it*4, swa = it & 7;
  #pragma unroll
  for (int kv = 0; kv < 8; ++kv) {
    float4 w0 = *(const float4*)&Wp[(kv*4+0)*36 + jt*4];
    float4 w1 = *(const float4*)&Wp[(kv*4+1)*36 + jt*4];
    float4 w2 = *(const float4*)&Wp[(kv*4+2)*36 + jt*4];
    float4 w3 = *(const float4*)&Wp[(kv*4+3)*36 + jt*4];
    #pragma unroll
    for (int d = 0; d < 4; ++d) {
      float4 a = *(const float4*)&S[(i0+d)*32 + ((kv ^ swa) << 2)];
      acc[d][0] += a.x*w0.x + a.y*w1.x + a.z*w2.x + a.w*w3.x;
      acc[d][1] += a.x*w0.y + a.y*w1.y + a.z*w2.y + a.w*w3.y;
      acc[d][2] += a.x*w0.z + a.y*w1.z + a.z*w2.z + a.w*w3.z;
      acc[d][3] += a.x*w0.w + a.y*w1.w + a.z*w2.w + a.w*w3.w;
    }
  }
}

// ---------------------------------------------------------------------------
// kG1: gA[g][dd] = dinv[dd] * (x[onode[dd]] @ Wg0).  grid (G,2) x 512.
// ---------------------------------------------------------------------------
__global__ __launch_bounds__(512, 4) void kG1(
    const float* __restrict__ x1, const float* __restrict__ x2,
    const float* __restrict__ Wg0, float* __restrict__ ws)
{
  int g = blockIdx.x, half = blockIdx.y, br = g >> 6, b = g & 63;
  const float* xg = (br ? x2 : x1) + (size_t)b*N_*F_;
  const int* onodeg = (const int*)ws + WS_ONODE + (size_t)g*K_ + half*256;
  const float* dinvg = ws + WS_DINV + (size_t)g*K_ + half*256;
  float* gAg = ws + WS_GA + (size_t)g*K_*H_ + (size_t)half*256*H_;

  __shared__ float wbuf[F_*36];   // 18KB
  __shared__ int   onodeL[256];
  __shared__ float dinvL[256];

  int t = threadIdx.x;
  for (int i = t; i < F_*H_; i += 512) wbuf[(i >> 5)*36 + (i & 31)] = Wg0[i];
  if (t < 256) { onodeL[t] = onodeg[t]; dinvL[t] = dinvg[t]; }
  __syncthreads();

  const int it = t >> 3, jt = t & 7;
  const int i0 = it*4;
  const float* xr0 = xg + (size_t)onodeL[i0+0]*F_;
  const float* xr1 = xg + (size_t)onodeL[i0+1]*F_;
  const float* xr2 = xg + (size_t)onodeL[i0+2]*F_;
  const float* xr3 = xg + (size_t)onodeL[i0+3]*F_;
  float acc[4][4] = {};
  for (int k4 = 0; k4 < 32; ++k4) {
    float4 w0 = *(const float4*)&wbuf[(k4*4+0)*36 + jt*4];
    float4 w1 = *(const float4*)&wbuf[(k4*4+1)*36 + jt*4];
    float4 w2 = *(const float4*)&wbuf[(k4*4+2)*36 + jt*4];
    float4 w3 = *(const float4*)&wbuf[(k4*4+3)*36 + jt*4];
    float4 a;
    a = *(const float4*)(xr0 + k4*4);
    acc[0][0]+=a.x*w0.x+a.y*w1.x+a.z*w2.x+a.w*w3.x; acc[0][1]+=a.x*w0.y+a.y*w1.y+a.z*w2.y+a.w*w3.y;
    acc[0][2]+=a.x*w0.z+a.y*w1.z+a.z*w2.z+a.w*w3.z; acc[0][3]+=a.x*w0.w+a.y*w1.w+a.z*w2.w+a.w*w3.w;
    a = *(const float4*)(xr1 + k4*4);
    acc[1][0]+=a.x*w0.x+a.y*w1.x+a.z*w2.x+a.w*w3.x; acc[1][1]+=a.x*w0.y+a.y*w1.y+a.z*w2.y+a.w*w3.y;
    acc[1][2]+=a.x*w0.z+a.y*w1.z+a.z*w2.z+a.w*w3.z; acc[1][3]+=a.x*w0.w+a.y*w1.w+a.z*w2.w+a.w*w3.w;
    a = *(const float4*)(xr2 + k4*4);
    acc[2][0]+=a.x*w0.x+a.y*w1.x+a.z*w2.x+a.w*w3.x; acc[2][1]+=a.x*w0.y+a.y*w1.y+a.z*w2.y+a.w*w3.y;
    acc[2][2]+=a.x*w0.z+a.y*w1.z+a.z*w2.z+a.w*w3.z; acc[2][3]+=a.x*w0.w+a.y*w1.w+a.z*w2.w+a.w*w3.w;
    a = *(const float4*)(xr3 + k4*4);
    acc[3][0]+=a.x*w0.x+a.y*w1.x+a.z*w2.x+a.w*w3.x; acc[3][1]+=a.x*w0.y+a.y*w1.y+a.z*w2.y+a.w*w3.y;
    acc[3][2]+=a.x*w0.z+a.y*w1.z+a.z*w2.z+a.w*w3.z; acc[3][3]+=a.x*w0.w+a.y*w1.w+a.z*w2.w+a.w*w3.w;
  }
  #pragma unroll
  for (int d = 0; d < 4; ++d) {
    int row = i0 + d;
    float rs = dinvL[row];
    float4 o; o.x=acc[d][0]*rs; o.y=acc[d][1]*rs; o.z=acc[d][2]*rs; o.w=acc[d][3]*rs;
    *(float4*)&gAg[row*32 + jt*4] = o;
  }
}

// ---------------------------------------------------------------------------
// conv gather from global feature buffer into swizzled LDS c-buffer.
// 512 threads: ddl = t&255, hc = t>>8 (16 cols each).
// ---------------------------------------------------------------------------
static __device__ __forceinline__ void convG(
    const float* __restrict__ gS, float* __restrict__ cbuf,
    const float* __restrict__ bias, const float* __restrict__ dinvL,
    const int* __restrict__ eoffL, const int* __restrict__ vcntL,
    const uint16_t* __restrict__ srcS, int half, int t)
{
  int ddl = t & 255, hc = t >> 8;
  int dd = half*256 + ddl;
  int lo = eoffL[ddl], n = vcntL[ddl];
  int c0 = hc*16;
  float4 a0 = {0,0,0,0}, a1 = a0, a2 = a0, a3 = a0;
  for (int i = 0; i < n; ++i) {
    int ss = srcS[lo + i];
    const float* r = gS + ss*32 + c0;
    float4 v;
    v = *(const float4*)(r+0);  a0.x+=v.x; a0.y+=v.y; a0.z+=v.z; a0.w+=v.w;
    v = *(const float4*)(r+4);  a1.x+=v.x; a1.y+=v.y; a1.z+=v.z; a1.w+=v.w;
    v = *(const float4*)(r+8);  a2.x+=v.x; a2.y+=v.y; a2.z+=v.z; a2.w+=v.w;
    v = *(const float4*)(r+12); a3.x+=v.x; a3.y+=v.y; a3.z+=v.z; a3.w+=v.w;
  }
  { const float* r = gS + dd*32 + c0;
    float4 v;
    v = *(const float4*)(r+0);  a0.x+=v.x; a0.y+=v.y; a0.z+=v.z; a0.w+=v.w;
    v = *(const float4*)(r+4);  a1.x+=v.x; a1.y+=v.y; a1.z+=v.z; a1.w+=v.w;
    v = *(const float4*)(r+8);  a2.x+=v.x; a2.y+=v.y; a2.z+=v.z; a2.w+=v.w;
    v = *(const float4*)(r+12); a3.x+=v.x; a3.y+=v.y; a3.z+=v.z; a3.w+=v.w; }
  float dvd = dinvL[ddl];
  float4 r0, r1, r2, r3;
  r0.x = dvd*a0.x + bias[c0+0];  r0.y = dvd*a0.y + bias[c0+1];
  r0.z = dvd*a0.z + bias[c0+2];  r0.w = dvd*a0.w + bias[c0+3];
  r1.x = dvd*a1.x + bias[c0+4];  r1.y = dvd*a1.y + bias[c0+5];
  r1.z = dvd*a1.z + bias[c0+6];  r1.w = dvd*a1.w + bias[c0+7];
  r2.x = dvd*a2.x + bias[c0+8];  r2.y = dvd*a2.y + bias[c0+9];
  r2.z = dvd*a2.z + bias[c0+10]; r2.w = dvd*a2.w + bias[c0+11];
  r3.x = dvd*a3.x + bias[c0+12]; r3.y = dvd*a3.y + bias[c0+13];
  r3.z = dvd*a3.z + bias[c0+14]; r3.w = dvd*a3.w + bias[c0+15];
  int g4 = hc*4;
  *(float4*)&cbuf[swzf4(ddl, g4+0)] = r0;
  *(float4*)&cbuf[swzf4(ddl, g4+1)] = r1;
  *(float4*)&cbuf[swzf4(ddl, g4+2)] = r2;
  *(float4*)&cbuf[swzf4(ddl, g4+3)] = r3;
}

// ---------------------------------------------------------------------------
// kG2: conv0 -> r0=relu(.@Wm0a+b) -> {column partials, gC=(r0@W01+b01)*dinv}
// grid (G,2) x 512. LDS ~84KB.
// ---------------------------------------------------------------------------
__global__ __launch_bounds__(512, 4) void kG2(
    const float* __restrict__ bg0,
    const float* __restrict__ Wm0a, const float* __restrict__ bm0a,
    float* __restrict__ ws)
{
  int g = blockIdx.x, half = blockIdx.y;
  const float* gAg = ws + WS_GA + (size_t)g*K_*H_;
  float* gCg = ws + WS_GC + (size_t)g*K_*H_;
  const uint16_t* srcS = (const uint16_t*)(ws + WS_SRCS) + (size_t)g*E_;
  const int* eoffg = (const int*)ws + WS_EOFF + (size_t)g*K_ + half*256;
  const uint16_t* vdegg = (const uint16_t*)(ws + WS_VDEG) + (size_t)g*K_ + half*256;
  const float* dinvg = ws + WS_DINV + (size_t)g*K_ + half*256;

  __shared__ float cbufA[256*32];  // 32KB
  __shared__ float cbufB[256*32];  // 32KB
  __shared__ float wA[32*36];      // 4.5KB Wm0a
  __shared__ float wB[32*36];      // 4.5KB W01
  __shared__ float scrP[64*33];    // 8.4KB
  __shared__ int   eoffL[256];
  __shared__ int   vcntL[256];
  __shared__ float dinvL[256];

  int t = threadIdx.x;
  for (int i = t; i < 1024; i += 512) {
    int k = i >> 5, j = i & 31;
    wA[k*36+j] = Wm0a[i];
    wB[k*36+j] = ws[WS_W01 + i];
  }
  if (t < 256) { eoffL[t] = eoffg[t]; vcntL[t] = vdegg[t]; dinvL[t] = dinvg[t]; }
  __syncthreads();

  convG(gAg, cbufA, bg0, dinvL, eoffL, vcntL, srcS, half, t);
  __syncthreads();

  const int it = t >> 3, jt = t & 7;
  float acc[4][4] = {};
  mmA(cbufA, wA, acc, it, jt);
  {
    float b0 = bm0a[jt*4+0], b1 = bm0a[jt*4+1], b2 = bm0a[jt*4+2], b3 = bm0a[jt*4+3];
    float cp0=0.f, cp1=0.f, cp2=0.f, cp3=0.f;
    #pragma unroll
    for (int d = 0; d < 4; ++d) {
      float v0=fmaxf(acc[d][0]+b0,0.f), v1=fmaxf(acc[d][1]+b1,0.f);
      float v2=fmaxf(acc[d][2]+b2,0.f), v3=fmaxf(acc[d][3]+b3,0.f);
      cp0+=v0; cp1+=v1; cp2+=v2; cp3+=v3;
      float4 o; o.x=v0; o.y=v1; o.z=v2; o.w=v3;
      *(float4*)&cbufB[swzf4(it*4+d, jt)] = o;
    }
    scrP[it*33 + jt*4+0] = cp0; scrP[it*33 + jt*4+1] = cp1;
    scrP[it*33 + jt*4+2] = cp2; scrP[it*33 + jt*4+3] = cp3;
  }
  __syncthreads();

  if (t < 32) {
    float s = 0.f;
    #pragma unroll
    for (int q = 0; q < 64; ++q) s += scrP[q*33 + t];
    ws[WS_PM0 + (size_t)g*64 + half*32 + t] = s;
  }

  // gC = (r0 @ W01 + b01) * dinv
  float acc2[4][4] = {};
  mmA(cbufB, wB, acc2, it, jt);
  {
    float b0 = ws[WS_B01+jt*4+0], b1 = ws[WS_B01+jt*4+1];
    float b2 = ws[WS_B01+jt*4+2], b3 = ws[WS_B01+jt*4+3];
    #pragma unroll
    for (int d = 0; d < 4; ++d) {
      int row = it*4 + d;
      float rs = dinvL[row];
      float4 o;
      o.x=(acc2[d][0]+b0)*rs; o.y=(acc2[d][1]+b1)*rs;
      o.z=(acc2[d][2]+b2)*rs; o.w=(acc2[d][3]+b3)*rs;
      *(float4*)&gCg[(half*256+row)*32 + jt*4] = o;
    }
  }
}

// ---------------------------------------------------------------------------
// kG4: conv1 -> r1=relu(.@Wm1a+b) -> column partials.  grid (G,2) x 512.
// ---------------------------------------------------------------------------
__global__ __launch_bounds__(512, 4) void kG4(
    const float* __restrict__ bg1,
    const float* __restrict__ Wm1a, const float* __restrict__ bm1a,
    float* __restrict__ ws)
{
  int g = blockIdx.x, half = blockIdx.y;
  const float* gCg = ws + WS_GC + (size_t)g*K_*H_;
  const uint16_t* srcS = (const uint16_t*)(ws + WS_SRCS) + (size_t)g*E_;
  const int* eoffg = (const int*)ws + WS_EOFF + (size_t)g*K_ + half*256;
  const uint16_t* vdegg = (const uint16_t*)(ws + WS_VDEG) + (size_t)g*K_ + half*256;
  const float* dinvg = ws + WS_DINV + (size_t)g*K_ + half*256;

  __shared__ float cbufA[256*32];  // 32KB
  __shared__ float wA[32*36];      // 4.5KB Wm1a
  __shared__ float scrP[64*33];    // 8.4KB
  __shared__ int   eoffL[256];
  __shared__ int   vcntL[256];
  __shared__ float dinvL[256];

  int t = threadIdx.x;
  for (int i = t; i < 1024; i += 512) wA[(i>>5)*36 + (i&31)] = Wm1a[i];
  if (t < 256) { eoffL[t] = eoffg[t]; vcntL[t] = vdegg[t]; dinvL[t] = dinvg[t]; }
  __syncthreads();

  convG(gCg, cbufA, bg1, dinvL, eoffL, vcntL, srcS, half, t);
  __syncthreads();

  const int it = t >> 3, jt = t & 7;
  float acc[4][4] = {};
  mmA(cbufA, wA, acc, it, jt);
  {
    float b0 = bm1a[jt*4+0], b1 = bm1a[jt*4+1], b2 = bm1a[jt*4+2], b3 = bm1a[jt*4+3];
    float cp0=0.f, cp1=0.f, cp2=0.f, cp3=0.f;
    #pragma unroll
    for (int d = 0; d < 4; ++d) {
      cp0 += fmaxf(acc[d][0]+b0,0.f); cp1 += fmaxf(acc[d][1]+b1,0.f);
      cp2 += fmaxf(acc[d][2]+b2,0.f); cp3 += fmaxf(acc[d][3]+b3,0.f);
    }
    scrP[it*33 + jt*4+0] = cp0; scrP[it*33 + jt*4+1] = cp1;
    scrP[it*33 + jt*4+2] = cp2; scrP[it*33 + jt*4+3] = cp3;
  }
  __syncthreads();

  if (t < 32) {
    float s = 0.f;
    #pragma unroll
    for (int q = 0; q < 64; ++q) s += scrP[q*33 + t];
    ws[WS_PM1 + (size_t)g*64 + half*32 + t] = s;
  }
}

// ---------------------------------------------------------------------------
// k4: PI conv + relu, reduced by g0v/g2v. thread=(jp,sub) + shfl.
// ---------------------------------------------------------------------------
__global__ __launch_bounds__(256) void k4_pi(
    const float* __restrict__ PI1, const float* __restrict__ PI2,
    const float* __restrict__ Kc, const float* __restrict__ bc,
    float* __restrict__ ws)
{
  int g = blockIdx.x, br = g >> 6, b = g & 63;
  const float* pig = (br ? PI2 : PI1) + (size_t)b*CF_*P_*P_;
  __shared__ float PIt[CF_*P_*P_];   // 50KB
  __shared__ float KcL[H_*CF_*4];
  __shared__ float bcL[H_], g0L[H_], g2L[PO];
  int t = threadIdx.x;
  for (int i = t; i < CF_*P_*P_; i += 256) PIt[i] = pig[i];
  for (int i = t; i < H_*CF_*4; i += 256) KcL[i] = Kc[i];
  if (t < 32) { bcL[t] = bc[t]; g0L[t] = ws[WS_G0V + t]; }
  if (t >= 32 && t < 32+PO) g2L[t-32] = ws[WS_G2V + (t-32)];
  __syncthreads();
  int jp = t >> 3, sub = t & 7;
  float acc = 0.f;
  if (jp < PO) {
    for (int i = sub; i < H_; i += 8) {
      const float* kcp = &KcL[i*20];
      float bi = bcL[i], gi = g0L[i];
      for (int kp = 0; kp < PO; ++kp) {
        float v = bi;
        #pragma unroll
        for (int c = 0; c < CF_; ++c) {
          const float* pp = &PIt[c*2500 + (2*jp)*50 + 2*kp];
          v += pp[0]*kcp[c*4+0] + pp[1]*kcp[c*4+1] + pp[50]*kcp[c*4+2] + pp[51]*kcp[c*4+3];
        }
        acc += fmaxf(v, 0.f) * gi * g2L[kp];
      }
    }
  }
  #pragma unroll
  for (int d = 4; d > 0; d >>= 1) acc += __shfl_down(acc, d, 8);
  if (sub == 0 && jp < PO) ws[WS_PPI + (size_t)g*32 + jp] = acc;
}

// ---------------------------------------------------------------------------
// k5: per-graph tail via folded P0b/P1b. grid G x 64.
// ---------------------------------------------------------------------------
__global__ __launch_bounds__(64) void k5_final(
    const float* __restrict__ F1w, const float* __restrict__ G1w,
    const float* __restrict__ H1w, const float* __restrict__ Wo1,
    const float* __restrict__ bo1, const float* __restrict__ Wo2,
    const float* __restrict__ bo2, const float* __restrict__ ws,
    float* __restrict__ out)
{
  int g = blockIdx.x, t = threadIdx.x;
  __shared__ float mr0[32], mr1[32], AL[32], TL[32], pl[32], zl[32], ppiL[PO];
  if (t < 32) {
    mr0[t] = (ws[WS_PM0 + (size_t)g*64 + t] + ws[WS_PM0 + (size_t)g*64 + 32 + t]) * (1.f/512.f);
    mr1[t] = (ws[WS_PM1 + (size_t)g*64 + t] + ws[WS_PM1 + (size_t)g*64 + 32 + t]) * (1.f/512.f);
  }
  if (t >= 32 && t < 32+PO) ppiL[t-32] = ws[WS_PPI + (size_t)g*32 + (t-32)];
  __syncthreads();
  float f00 = ws[WS_F0V], f01 = ws[WS_F0V+1];
  if (t < 32) {
    float s0 = ws[WS_C0B + t], s1 = ws[WS_C1B + t];
    for (int k = 0; k < 32; ++k) {
      s0 += mr0[k]*ws[WS_P0B + k*32 + t];
      s1 += mr1[k]*ws[WS_P1B + k*32 + t];
    }
    AL[t] = f00*s0 + f01*s1;
  }
  __syncthreads();
  if (t < 32) {
    float s = 0.f;
    for (int jp = 0; jp < 32; ++jp) s += F1w[t*32+jp]*AL[jp];
    for (int jp = 0; jp < PO; ++jp) s += G1w[t*25+jp]*ppiL[jp];
    TL[t] = s;
  }
  __syncthreads();
  if (t < 32) {
    float s = 0.f;
    for (int j = 0; j < 32; ++j) s += H1w[t*32+j]*TL[j];
    pl[t] = s;
  }
  __syncthreads();
  if (t < 32) {
    float s = bo1[t];
    for (int j = 0; j < 32; ++j) s += pl[j]*Wo1[j*32+t];
    zl[t] = fmaxf(s, 0.f);
  }
  __syncthreads();
  if (t < 2) {
    float s = bo2[t];
    for (int q = 0; q < 32; ++q) s += zl[q]*Wo2[q*2+t];
    int br = g >> 6, b = g & 63;
    out[br*(B_*2) + b*2 + t] = s;
  }
}

// ---------------------------------------------------------------------------
extern "C" void kernel_launch(void* const* d_in, const int* in_sizes, int n_in,
                              void* d_out, int out_size, void* d_ws, size_t ws_size,
                              hipStream_t stream) {
  (void)in_sizes; (void)n_in; (void)out_size; (void)ws_size;
  const float* x1      = (const float*)d_in[0];
  const int*   ei1     = (const int*)  d_in[1];
  const float* PI1     = (const float*)d_in[2];
  const float* x2      = (const float*)d_in[3];
  const int*   ei2     = (const int*)  d_in[4];
  const float* PI2     = (const float*)d_in[5];
  const float* W_score = (const float*)d_in[6];
  const float* b_score = (const float*)d_in[7];
  const float* W_gcn0  = (const float*)d_in[8];
  const float* b_gcn0  = (const float*)d_in[9];
  const float* Wm0a    = (const float*)d_in[10];
  const float* bm0a    = (const float*)d_in[11];
  const float* Wm0b    = (const float*)d_in[12];
  const float* bm0b    = (const float*)d_in[13];
  const float* W_gcn1  = (const float*)d_in[14];
  const float* b_gcn1  = (const float*)d_in[15];
  const float* Wm1a    = (const float*)d_in[16];
  const float* bm1a    = (const float*)d_in[17];
  const float* Wm1b    = (const float*)d_in[18];
  const float* bm1b    = (const float*)d_in[19];
  const float* F0w     = (const float*)d_in[20];
  const float* F1w     = (const float*)d_in[21];
  const float* F2w     = (const float*)d_in[22];
  const float* Kc      = (const float*)d_in[23];
  const float* bc      = (const float*)d_in[24];
  const float* G0w     = (const float*)d_in[25];
  const float* G1w     = (const float*)d_in[26];
  const float* G2w     = (const float*)d_in[27];
  const float* H0w     = (const float*)d_in[28];
  const float* H1w     = (const float*)d_in[29];
  const float* H2w     = (const float*)d_in[30];
  const float* Wo1     = (const float*)d_in[31];
  const float* bo1     = (const float*)d_in[32];
  const float* Wo2     = (const float*)d_in[33];
  const float* bo2     = (const float*)d_in[34];
  float* ws  = (float*)d_ws;
  float* out = (float*)d_out;

  k0_setup<<<7, 256, 0, stream>>>(F0w, F2w, G0w, G2w, H0w, H2w,
                                  Wm0b, bm0b, Wm1b, bm1b, W_gcn1, ws);
  kcsr<<<G_, 1024, 0, stream>>>(ei1, ei2, ws);
  k2_pool<<<G_, 1024, 0, stream>>>(x1, x2, W_score, b_score, ws);
  kG1<<<dim3(G_, 2), 512, 0, stream>>>(x1, x2, W_gcn0, ws);
  kG2<<<dim3(G_, 2), 512, 0, stream>>>(b_gcn0, Wm0a, bm0a, ws);
  kG4<<<dim3(G_, 2), 512, 0, stream>>>(b_gcn1, Wm1a, bm1a, ws);
  k4_pi<<<G_, 256, 0, stream>>>(PI1, PI2, Kc, bc, ws);
  k5_final<<<G_, 64, 0, stream>>>(F1w, G1w, H1w, Wo1, bo1, Wo2, bo2, ws, out);
}